// Round 7
// baseline (521.777 us; speedup 1.0000x reference)
//
#include <hip/hip_runtime.h>
#include <stdint.h>

typedef __attribute__((ext_vector_type(8))) short short8;
typedef __attribute__((ext_vector_type(4))) float f32x4;

#define MFMA16(a,b,c) __builtin_amdgcn_mfma_f32_16x16x32_bf16((a),(b),(c),0,0,0)

// async global->LDS DMA, 16B per lane; LDS dest = wave-uniform base + lane*16B
#define GLL16(g, l) __builtin_amdgcn_global_load_lds( \
    (const __attribute__((address_space(1))) void*)(g), \
    (__attribute__((address_space(3))) void*)(l), 16, 0, 0)

__device__ __forceinline__ unsigned short f2bf(float f){
  unsigned u = __builtin_bit_cast(unsigned, f);
  u += 0x7fffu + ((u >> 16) & 1u);
  return (unsigned short)(u >> 16);
}

static constexpr int HW_ = 50176;   // 224*224

// offset of element (row r 0..127, k c64 0..63) inside one 8192-elem panel,
// XOR-swizzled so ds_read_b128 of a 16-lane column slice is conflict-free
__device__ __forceinline__ int panel_off(int r, int c64){
  return r * 64 + ((((c64 >> 3) ^ (r & 7))) << 3) + (c64 & 7);
}

// ---------------- weights fp32 -> bf16 ----------------
// Wf: qkv B-fragment stream: chunk gid = ((h*8+kq)*6+t)*64+lane holds
//     W{q,k,v}[h*32+(t&1)*16+(lane&15)][kq*32+(lane>>4)*8 .. +8)
// Wob: out-proj panels (for k_gemm_out)
__global__ __launch_bounds__(256) void k_convw(const float* __restrict__ Wq, const float* __restrict__ Wk,
                        const float* __restrict__ Wv, const float* __restrict__ Wo,
                        unsigned short* __restrict__ Wf, unsigned short* __restrict__ Wob){
  int gid = blockIdx.x * 256 + threadIdx.x;   // grid 128 -> 32768
  if (gid < 24576){
    int lane = gid & 63;
    int r1 = gid >> 6;          // 0..383
    int t = r1 % 6;
    int r2 = r1 / 6;            // 0..63
    int kq = r2 & 7, hh = r2 >> 3;
    const float* W = (t < 2) ? Wq : (t < 4) ? Wk : Wv;
    int ch = hh * 32 + (t & 1) * 16 + (lane & 15);
    int k0 = kq * 32 + (lane >> 4) * 8;
    const float* src = W + ch * 256 + k0;
    float4 a = *(const float4*)src, b2 = *(const float4*)(src + 4);
    short8 v;
    v[0]=f2bf(a.x); v[1]=f2bf(a.y); v[2]=f2bf(a.z); v[3]=f2bf(a.w);
    v[4]=f2bf(b2.x); v[5]=f2bf(b2.y); v[6]=f2bf(b2.z); v[7]=f2bf(b2.w);
    *(short8*)(Wf + (size_t)gid * 8) = v;
  } else {
    int og = gid - 24576;       // 0..8191
    int o = og >> 5, ck = og & 31;
    const float* src = Wo + o * 256 + ck * 8;
    float4 a = *(const float4*)src, b2 = *(const float4*)(src + 4);
    short8 v;
    v[0]=f2bf(a.x); v[1]=f2bf(a.y); v[2]=f2bf(a.z); v[3]=f2bf(a.w);
    v[4]=f2bf(b2.x); v[5]=f2bf(b2.y); v[6]=f2bf(b2.z); v[7]=f2bf(b2.w);
    int kq = ck >> 3;
    int off = panel_off(o & 127, (ck & 7) * 8);
    *(short8*)(Wob + ((o >> 7) * 4 + kq) * 8192 + off) = v;
  }
}

// ---------------- x (B,C,H,W) f32 -> xw[b][win][px 49][256c pre-swizzled] bf16 ----------------
// block = (b, wh, cq16): reads 16 ch x 7 rows x 224 w coalesced (64 lanes = 16ch x full 64B line)
// LDS tile [ww 32][px 49][16 c] u16, chunk-swizzled (half^(px&1)) -> conflict-free scalar writes
__global__ __launch_bounds__(256) void k_xw(const float* __restrict__ x, unsigned short* __restrict__ xw){
  int bid = blockIdx.x;
  int cq = bid & 15, wh = (bid >> 4) & 31, b = bid >> 9;
  __shared__ __align__(16) unsigned short tile[25088];  // 49 KB
  int tid = threadIdx.x;
  for (int it = 0; it < 25; ++it){
    int idx = it * 256 + tid;
    if (idx < 6272){
      int c = idx & 15;
      int t2 = idx >> 4;                  // 0..391
      int r = t2 / 56;                    // const-divisor: compiler emits correct magic
      int w4 = t2 % 56;
      float4 v = *(const float4*)(x + ((size_t)(b * 256 + cq * 16 + c)) * HW_ + (wh * 7 + r) * 224 + w4 * 4);
      float vv[4] = {v.x, v.y, v.z, v.w};
      int w0 = w4 * 4;
      int ww = w0 / 7;
      int cl = w0 % 7;
#pragma unroll
      for (int i = 0; i < 4; ++i){
        int px = r * 7 + cl;
        tile[ww * 784 + px * 16 + (((c >> 3) ^ (px & 1)) << 3) + (c & 7)] = f2bf(vv[i]);
        if (++cl == 7){ cl = 0; ++ww; }
      }
    }
  }
  __syncthreads();
  size_t wb = ((size_t)(b * 1024 + wh * 32)) * 16384;
  for (int it = 0; it < 13; ++it){
    int id = it * 256 + tid;
    if (id < 3136){                       // 32 ww x 49 px x 2 halves
      int ww = id / 98;
      int rem = id - ww * 98;
      int px = rem >> 1, half = rem & 1;
      short8 v = *(const short8*)(tile + ww * 784 + px * 16 + ((half ^ (px & 1)) << 3));
      int cc = cq * 2 + half;             // global 8-ch chunk 0..31
      int pos = (cc & 24) | ((cc ^ px) & 7);
      *(short8*)(xw + wb + (size_t)ww * 16384 + px * 256 + pos * 8) = v;
    }
  }
}

// ---------------- fused: qkv GEMM + window attention ----------------
// block = 1 window (49 px pad 64), 8 waves = 8 heads, 128 KB LDS
// LDS elems (u16): [0..16384) q[64px][256c swz]; [16384..32768) k (same)
//                  attn phase: sP wave h at h*4096 (P[64q][64k'] swz)
// [32768..49152) vT[256ch][64px swz granules]
// [49152..65536) phase0/1: x[64px][256c swz] (DMA'd from xw); phase3: O (same swz)
__global__ __launch_bounds__(512) void k_fused(const unsigned short* __restrict__ xw,
                                               const unsigned short* __restrict__ Wf,
                                               unsigned short* __restrict__ attnP){
  int bid = blockIdx.x;
  int wg = (bid & 7) * 512 + (bid >> 3);    // 4096 = 8*512, ww-contiguous per XCD
  int b = wg >> 10;
  int win = wg & 1023;
  int wh = win >> 5, ww = win & 31;
  int tid = threadIdx.x;
  int lane = tid & 63;
  int h = tid >> 6;                          // wave = head

  __shared__ __align__(16) unsigned short lds[65536];   // 128 KB

  // ---- phase 0: zero pad rows + DMA 49 window rows from xw ----
  {
    if (tid < 448){                          // rows 50..63
      int rr = 50 + (tid >> 5), ch = tid & 31;
      short8 z = {};
      *(short8*)(lds + 49152 + rr * 256 + ch * 8) = z;
    }
    const unsigned short* xwin = xw + ((size_t)(b * 1024 + wh * 32 + ww)) * 16384;
#pragma unroll
    for (int c3 = 0; c3 < 3; ++c3){
      int k = c3 * 8 + h;                    // chunks 0..23 -> rows 2k, 2k+1
      int row = 2 * k + (lane >> 5);
      GLL16(xwin + row * 256 + (lane & 31) * 8, lds + 49152 + k * 512);
    }
    if (h == 0)                              // chunk 24: row 48 (lanes>=32 dup row48 -> LDS row 49)
      GLL16(xwin + 48 * 256 + (lane & 31) * 8, lds + 49152 + 24 * 512);
  }
  __syncthreads();

  // ---- phase 1: qkv GEMM; W streamed from L2 as B-frags, x from LDS ----
  f32x4 aq[4][2] = {}, ak[4][2] = {}, av[2][4] = {};
  for (int kq = 0; kq < 8; ++kq){
    short8 xf[4];
#pragma unroll
    for (int pt = 0; pt < 4; ++pt){
      int px = pt * 16 + (lane & 15);
      int chk = (kq * 4 + (lane >> 4)) ^ (px & 7);
      xf[pt] = *(const short8*)(lds + 49152 + px * 256 + chk * 8);
    }
    short8 wfr[6];
#pragma unroll
    for (int t = 0; t < 6; ++t)
      wfr[t] = *(const short8*)(Wf + ((size_t)((h * 8 + kq) * 6 + t) * 64 + lane) * 8);
#pragma unroll
    for (int pt = 0; pt < 4; ++pt){
      aq[pt][0] = MFMA16(xf[pt], wfr[0], aq[pt][0]);   // D[px][ch]
      aq[pt][1] = MFMA16(xf[pt], wfr[1], aq[pt][1]);
      ak[pt][0] = MFMA16(xf[pt], wfr[2], ak[pt][0]);
      ak[pt][1] = MFMA16(xf[pt], wfr[3], ak[pt][1]);
      av[0][pt] = MFMA16(wfr[4], xf[pt], av[0][pt]);   // D[ch][px] (transposed v)
      av[1][pt] = MFMA16(wfr[5], xf[pt], av[1][pt]);
    }
  }
  // write q,k -> region A   (D[px][ch]: lane col ch=lane&15, rows px=(lane>>4)*4+j)
#pragma unroll
  for (int pt = 0; pt < 4; ++pt)
#pragma unroll
    for (int t = 0; t < 2; ++t)
#pragma unroll
      for (int j = 0; j < 4; ++j){
        int px = pt * 16 + (lane >> 4) * 4 + j;
        int ch = h * 32 + t * 16 + (lane & 15);
        int pos = px * 256 + (((ch >> 3) ^ (px & 7)) << 3) + (ch & 7);
        lds[pos]         = f2bf(aq[pt][t][j]);
        lds[16384 + pos] = f2bf(ak[pt][t][j]);
      }
  // write vT -> region B   (D[ch][px]: lane col px=lane&15, rows ch=(lane>>4)*4+j)
#pragma unroll
  for (int ct = 0; ct < 2; ++ct)
#pragma unroll
    for (int pt = 0; pt < 4; ++pt)
#pragma unroll
      for (int j = 0; j < 4; ++j){
        int ch = h * 32 + ct * 16 + (lane >> 4) * 4 + j;
        int px = pt * 16 + (lane & 15);
        lds[32768 + ch * 64 + (((px >> 3) ^ (ch & 7)) << 3) + (px & 7)] = f2bf(av[ct][pt][j]);
      }
  __syncthreads();

  // ---- phase 2: S^T = K * Q^T ----
  short8 kf[4], qf[4];
#pragma unroll
  for (int i = 0; i < 4; ++i){
    int px = i * 16 + (lane & 15);
    int chk = (h * 4 + (lane >> 4)) ^ (px & 7);
    qf[i] = *(const short8*)(lds + px * 256 + chk * 8);
    kf[i] = *(const short8*)(lds + 16384 + px * 256 + chk * 8);
  }
  f32x4 s[4][4] = {};
#pragma unroll
  for (int mi = 0; mi < 4; ++mi)
#pragma unroll
    for (int ni = 0; ni < 4; ++ni)
      s[mi][ni] = MFMA16(kf[mi], qf[ni], s[mi][ni]);
  __syncthreads();                 // all q/k reads done; region A becomes sP

  // ---- softmax over k' per q column; write P bf16 to sP (wave-private 8 KB) ----
  const float cexp = 0.25504437f;  // log2(e)/sqrt(32)
  unsigned short* sP = lds + h * 4096;
#pragma unroll
  for (int ni = 0; ni < 4; ++ni){
    float m = -3.0e38f;
#pragma unroll
    for (int mi = 0; mi < 4; ++mi)
#pragma unroll
      for (int r = 0; r < 4; ++r){
        int kp = mi * 16 + ((lane >> 4) * 4) + r;
        if (kp < 49) m = fmaxf(m, s[mi][ni][r]);
      }
    m = fmaxf(m, __shfl_xor(m, 16));
    m = fmaxf(m, __shfl_xor(m, 32));
    float sum = 0.f;
    float pv[4][4];
#pragma unroll
    for (int mi = 0; mi < 4; ++mi)
#pragma unroll
      for (int r = 0; r < 4; ++r){
        int kp = mi * 16 + ((lane >> 4) * 4) + r;
        float e2 = (kp < 49) ? exp2f((s[mi][ni][r] - m) * cexp) : 0.f;
        pv[mi][r] = e2; sum += e2;
      }
    sum += __shfl_xor(sum, 16);
    sum += __shfl_xor(sum, 32);
    float inv = 1.0f / sum;
    int q = ni * 16 + (lane & 15);
#pragma unroll
    for (int mi = 0; mi < 4; ++mi)
#pragma unroll
      for (int r = 0; r < 4; ++r){
        int kp = mi * 16 + ((lane >> 4) * 4) + r;
        int bo = (q * 128 + kp * 2) ^ ((q & 7) << 4);
        sP[bo >> 1] = f2bf(pv[mi][r] * inv);
      }
  }

  // ---- phase 3: O = P * V ----
  f32x4 o[4][2] = {};
#pragma unroll
  for (int kc = 0; kc < 2; ++kc){
    short8 pa[4], vb[2];
#pragma unroll
    for (int mtp = 0; mtp < 4; ++mtp){
      int row = mtp * 16 + (lane & 15);
      int bo = (row * 128 + kc * 64 + (lane >> 4) * 16) ^ ((row & 7) << 4);
      pa[mtp] = *(const short8*)(sP + (bo >> 1));
    }
#pragma unroll
    for (int ntp = 0; ntp < 2; ++ntp){
      int ch = h * 32 + ntp * 16 + (lane & 15);
      int k0 = kc * 32 + (lane >> 4) * 8;
      vb[ntp] = *(const short8*)(lds + 32768 + ch * 64 + (((k0 >> 3) ^ (ch & 7)) << 3));
    }
#pragma unroll
    for (int mtp = 0; mtp < 4; ++mtp)
#pragma unroll
      for (int ntp = 0; ntp < 2; ++ntp)
        o[mtp][ntp] = MFMA16(pa[mtp], vb[ntp], o[mtp][ntp]);
  }
  // O -> region C (x dead since phase-1 barrier)
#pragma unroll
  for (int mtp = 0; mtp < 4; ++mtp)
#pragma unroll
    for (int ntp = 0; ntp < 2; ++ntp)
#pragma unroll
      for (int r = 0; r < 4; ++r){
        int px = mtp * 16 + (lane >> 4) * 4 + r;
        int ch = h * 32 + ntp * 16 + (lane & 15);
        lds[49152 + px * 256 + (((ch >> 3) ^ (px & 7)) << 3) + (ch & 7)] = f2bf(o[mtp][ntp][r]);
      }
  __syncthreads();

  // ---- phase 4: cooperative 16B panel stores ----
  size_t pb0 = (size_t)b * 392 * 4;
#pragma unroll
  for (int it = 0; it < 4; ++it){
    int id = it * 512 + tid;                 // 0..2047 = 64 px * 32 chunks
    int px = id >> 5, ck = id & 31;
    if (px < 49){
      short8 v = *(const short8*)(lds + 49152 + px * 256 + ((ck ^ (px & 7)) << 3));
      int pg = (wh * 7 + px / 7) * 224 + ww * 7 + px % 7;
      int nt = pg >> 7, pr = pg & 127;
      size_t off = (pb0 + (size_t)nt * 4 + (ck >> 3)) * 8192 + panel_off(pr, (ck & 7) * 8);
      *(short8*)(attnP + off) = v;
    }
  }
}

// ---------------- GEMM out + residual + per-block BN partials (no atomics) ----------------
__global__ __launch_bounds__(256) void k_gemm_out(const unsigned short* __restrict__ Wp,
                                                  const unsigned short* __restrict__ Bp,
                                                  const float* __restrict__ x,
                                                  float* __restrict__ y,
                                                  float* __restrict__ partials){
  int bid = blockIdx.x;
  int wg = (bid & 7) * 392 + (bid >> 3);     // 3136 = 8*392
  int mt = wg & 1; int rest = wg >> 1;       // mt fastest
  int nt = rest % 392; int b = rest / 392;

  __shared__ __align__(16) unsigned short lds[32768];  // dbuf

  int tid = threadIdx.x;
  int lane = tid & 63;
  int wave = tid >> 6;
  int wm = wave >> 1, wn = wave & 1;

  const unsigned short* Apan = Wp + (size_t)mt * 4 * 8192;
  const unsigned short* Bpan = Bp + ((size_t)(b * 392 + nt)) * 4 * 8192;

  int aoff[2][4], boff[2][4];
#pragma unroll
  for (int kk = 0; kk < 2; ++kk)
#pragma unroll
    for (int i = 0; i < 4; ++i){
      int rowA = wm * 64 + i * 16 + (lane & 15);
      aoff[kk][i] = rowA * 64 + (((kk * 4 + (lane >> 4)) ^ (rowA & 7)) << 3);
      int rowB = wn * 64 + i * 16 + (lane & 15);
      boff[kk][i] = rowB * 64 + (((kk * 4 + (lane >> 4)) ^ (rowB & 7)) << 3);
    }
  int cb = wave * 2048;
  f32x4 acc[4][4] = {};

#pragma unroll
  for (int j = 0; j < 4; ++j){
    int o2 = cb + j * 512;
    GLL16(Apan + o2 + lane * 8, lds + o2);
    GLL16(Bpan + o2 + lane * 8, lds + 8192 + o2);
  }
  __syncthreads();

  int cur = 0;
  for (int kq = 0; kq < 4; ++kq){
    if (kq < 3){
      const unsigned short* Ak = Apan + (kq + 1) * 8192;
      const unsigned short* Bk = Bpan + (kq + 1) * 8192;
      unsigned short* dst = lds + (cur ^ 1) * 16384;
#pragma unroll
      for (int j = 0; j < 4; ++j){
        int o2 = cb + j * 512;
        GLL16(Ak + o2 + lane * 8, dst + o2);
        GLL16(Bk + o2 + lane * 8, dst + 8192 + o2);
      }
    }
    const unsigned short* Alds = lds + cur * 16384;
    const unsigned short* Blds = Alds + 8192;
#pragma unroll
    for (int kk = 0; kk < 2; ++kk){
      short8 af[4], bfv[4];
#pragma unroll
      for (int i = 0; i < 4; ++i) af[i]  = *(const short8*)(Alds + aoff[kk][i]);
#pragma unroll
      for (int j = 0; j < 4; ++j) bfv[j] = *(const short8*)(Blds + boff[kk][j]);
#pragma unroll
      for (int i = 0; i < 4; ++i)
#pragma unroll
        for (int j = 0; j < 4; ++j)
          acc[i][j] = MFMA16(af[i], bfv[j], acc[i][j]);
    }
    __syncthreads();
    cur ^= 1;
  }
  // epilogue: residual add, fp32 store, per-channel partial sums
  float ps[4][4] = {}, pq[4][4] = {};
#pragma unroll
  for (int i = 0; i < 4; ++i)
#pragma unroll
    for (int j = 0; j < 4; ++j){
      int o = mt * 128 + wm * 64 + i * 16 + (lane >> 4) * 4;
      int p = nt * 128 + wn * 64 + j * 16 + (lane & 15);
      size_t base = ((size_t)(b * 256 + o)) * HW_ + p;
#pragma unroll
      for (int r2 = 0; r2 < 4; ++r2){
        float v = acc[i][j][r2] + x[base + (size_t)r2 * HW_];
        y[base + (size_t)r2 * HW_] = v;
        ps[i][r2] += v;
        pq[i][r2] += v * v;
      }
    }
  float* fl = (float*)lds;    // [wn 2][cl 128] sums, +256 sq
#pragma unroll
  for (int i = 0; i < 4; ++i)
#pragma unroll
    for (int r2 = 0; r2 < 4; ++r2){
      float a = ps[i][r2], q2 = pq[i][r2];
      a += __shfl_xor(a, 1);  q2 += __shfl_xor(q2, 1);
      a += __shfl_xor(a, 2);  q2 += __shfl_xor(q2, 2);
      a += __shfl_xor(a, 4);  q2 += __shfl_xor(q2, 4);
      a += __shfl_xor(a, 8);  q2 += __shfl_xor(q2, 8);
      if ((lane & 15) == 0){
        int cl = wm * 64 + i * 16 + (lane >> 4) * 4 + r2;
        fl[wn * 128 + cl] = a;
        fl[256 + wn * 128 + cl] = q2;
      }
    }
  __syncthreads();
  if (tid < 128){
    partials[(size_t)wg * 256 + tid]       = fl[tid] + fl[128 + tid];
    partials[(size_t)wg * 256 + 128 + tid] = fl[256 + tid] + fl[384 + tid];
  }
}

// ---------------- reduce per-block partials -> mean / rsqrt ----------------
__global__ __launch_bounds__(256) void k_stats2(const float* __restrict__ partials, float* __restrict__ stats){
  int c = blockIdx.x;           // 0..255
  int mt = c >> 7, cl = c & 127;
  int t = threadIdx.x;
  float s = 0.f, q = 0.f;
  for (int idx = t; idx < 1568; idx += 256){
    const float* p = partials + (size_t)(2 * idx + mt) * 256;
    s += p[cl]; q += p[128 + cl];
  }
  __shared__ float r1[256], r2[256];
  r1[t] = s; r2[t] = q; __syncthreads();
  for (int off = 128; off > 0; off >>= 1){
    if (t < off){ r1[t] += r1[t + off]; r2[t] += r2[t + off]; }
    __syncthreads();
  }
  if (t == 0){
    float mean = r1[0] * (1.f / 200704.f);
    float var  = r2[0] * (1.f / 200704.f) - mean * mean;
    stats[c] = mean;
    stats[256 + c] = rsqrtf(var + 1e-5f);
  }
}

// ---------------- in-place normalize ----------------
__global__ __launch_bounds__(256) void k_norm(float* __restrict__ y, const float* __restrict__ stats,
                                              const float* __restrict__ gamma, const float* __restrict__ beta){
  const long long total = 12845056LL;  // 51380224 / 4
  for (long long idx = (long long)blockIdx.x * 256 + threadIdx.x; idx < total; idx += (long long)gridDim.x * 256){
    int c = (int)((idx / 12544) & 255);
    float sc = stats[256 + c] * gamma[c];
    float sh = beta[c] - stats[c] * sc;
    float4* p = (float4*)y + idx;
    float4 v = *p;
    v.x = v.x * sc + sh; v.y = v.y * sc + sh; v.z = v.z * sc + sh; v.w = v.w * sc + sh;
    *p = v;
  }
}

extern "C" void kernel_launch(void* const* d_in, const int* in_sizes, int n_in,
                              void* d_out, int out_size, void* d_ws, size_t ws_size,
                              hipStream_t stream){
  const float* x     = (const float*)d_in[0];
  const float* Wq    = (const float*)d_in[1];
  const float* Wk    = (const float*)d_in[2];
  const float* Wv    = (const float*)d_in[3];
  const float* Wo    = (const float*)d_in[4];
  const float* gamma = (const float*)d_in[5];
  const float* beta  = (const float*)d_in[6];
  float* out = (float*)d_out;

  char* ws = (char*)d_ws;
  unsigned short* Wf     = (unsigned short*)ws;                               // 393216 B
  unsigned short* Wo_b   = (unsigned short*)(ws + 393216);                    // 131072 B
  float*          stats  = (float*)(ws + 524288);                             // 2048 B
  unsigned short* xw     = (unsigned short*)(ws + 1048576);                   // 134217728 B
  unsigned short* attnP  = (unsigned short*)(ws + 1048576 + 134217728);       // 102760448 B
  float*          partials = (float*)(ws + 1048576 + 134217728 + 102760448);  // 3211264 B

  k_convw<<<128, 256, 0, stream>>>(Wq, Wk, Wv, Wo, Wf, Wo_b);
  k_xw<<<2048, 256, 0, stream>>>(x, xw);
  k_fused<<<4096, 512, 0, stream>>>(xw, Wf, attnP);
  k_gemm_out<<<3136, 256, 0, stream>>>(Wo_b, attnP, x, out, partials);
  k_stats2<<<256, 256, 0, stream>>>(partials, stats);
  k_norm<<<4096, 256, 0, stream>>>(out, stats, gamma, beta);
}

// Round 8
// 503.058 us; speedup vs baseline: 1.0372x; 1.0372x over previous
//
#include <hip/hip_runtime.h>
#include <stdint.h>

typedef __attribute__((ext_vector_type(8))) short short8;
typedef __attribute__((ext_vector_type(4))) float f32x4;

#define MFMA16(a,b,c) __builtin_amdgcn_mfma_f32_16x16x32_bf16((a),(b),(c),0,0,0)

// async global->LDS DMA, 16B per lane; LDS dest = wave-uniform base + lane*16B
#define GLL16(g, l) __builtin_amdgcn_global_load_lds( \
    (const __attribute__((address_space(1))) void*)(g), \
    (__attribute__((address_space(3))) void*)(l), 16, 0, 0)

__device__ __forceinline__ unsigned short f2bf(float f){
  unsigned u = __builtin_bit_cast(unsigned, f);
  u += 0x7fffu + ((u >> 16) & 1u);
  return (unsigned short)(u >> 16);
}
__device__ __forceinline__ float bf2f(unsigned short s){
  unsigned u = ((unsigned)s) << 16;
  return __builtin_bit_cast(float, u);
}

static constexpr int HW_ = 50176;   // 224*224

// offset of element (row r 0..127, k c64 0..63) inside one 8192-elem panel,
// XOR-swizzled so ds_read_b128 of a 16-lane column slice is conflict-free
__device__ __forceinline__ int panel_off(int r, int c64){
  return r * 64 + ((((c64 >> 3) ^ (r & 7))) << 3) + (c64 & 7);
}

// ---------------- weights fp32 -> bf16 ----------------
// Wf: qkv B-fragment stream: chunk gid = ((h*8+kq)*6+t)*64+lane holds
//     W{q,k,v}[h*32+(t&1)*16+(lane&15)][kq*32+(lane>>4)*8 .. +8)
// Wob: out-proj panels (for k_gemm_out)
__global__ __launch_bounds__(256) void k_convw(const float* __restrict__ Wq, const float* __restrict__ Wk,
                        const float* __restrict__ Wv, const float* __restrict__ Wo,
                        unsigned short* __restrict__ Wf, unsigned short* __restrict__ Wob){
  int gid = blockIdx.x * 256 + threadIdx.x;   // grid 128 -> 32768
  if (gid < 24576){
    int lane = gid & 63;
    int r1 = gid >> 6;          // 0..383
    int t = r1 % 6;
    int r2 = r1 / 6;            // 0..63
    int kq = r2 & 7, hh = r2 >> 3;
    const float* W = (t < 2) ? Wq : (t < 4) ? Wk : Wv;
    int ch = hh * 32 + (t & 1) * 16 + (lane & 15);
    int k0 = kq * 32 + (lane >> 4) * 8;
    const float* src = W + ch * 256 + k0;
    float4 a = *(const float4*)src, b2 = *(const float4*)(src + 4);
    short8 v;
    v[0]=f2bf(a.x); v[1]=f2bf(a.y); v[2]=f2bf(a.z); v[3]=f2bf(a.w);
    v[4]=f2bf(b2.x); v[5]=f2bf(b2.y); v[6]=f2bf(b2.z); v[7]=f2bf(b2.w);
    *(short8*)(Wf + (size_t)gid * 8) = v;
  } else {
    int og = gid - 24576;       // 0..8191
    int o = og >> 5, ck = og & 31;
    const float* src = Wo + o * 256 + ck * 8;
    float4 a = *(const float4*)src, b2 = *(const float4*)(src + 4);
    short8 v;
    v[0]=f2bf(a.x); v[1]=f2bf(a.y); v[2]=f2bf(a.z); v[3]=f2bf(a.w);
    v[4]=f2bf(b2.x); v[5]=f2bf(b2.y); v[6]=f2bf(b2.z); v[7]=f2bf(b2.w);
    int kq = ck >> 3;
    int off = panel_off(o & 127, (ck & 7) * 8);
    *(short8*)(Wob + ((o >> 7) * 4 + kq) * 8192 + off) = v;
  }
}

// ---------------- x (B,C,H,W) f32 -> xw[b][win][px 49][256c pre-swizzled] bf16 ----------------
__global__ __launch_bounds__(256) void k_xw(const float* __restrict__ x, unsigned short* __restrict__ xw){
  int bid = blockIdx.x;
  int cq = bid & 15, wh = (bid >> 4) & 31, b = bid >> 9;
  __shared__ __align__(16) unsigned short tile[25088];  // 49 KB
  int tid = threadIdx.x;
  for (int it = 0; it < 25; ++it){
    int idx = it * 256 + tid;
    if (idx < 6272){
      int c = idx & 15;
      int t2 = idx >> 4;                  // 0..391
      int r = t2 / 56;
      int w4 = t2 % 56;
      float4 v = *(const float4*)(x + ((size_t)(b * 256 + cq * 16 + c)) * HW_ + (wh * 7 + r) * 224 + w4 * 4);
      float vv[4] = {v.x, v.y, v.z, v.w};
      int w0 = w4 * 4;
      int ww = w0 / 7;
      int cl = w0 % 7;
#pragma unroll
      for (int i = 0; i < 4; ++i){
        int px = r * 7 + cl;
        tile[ww * 784 + px * 16 + (((c >> 3) ^ (px & 1)) << 3) + (c & 7)] = f2bf(vv[i]);
        if (++cl == 7){ cl = 0; ++ww; }
      }
    }
  }
  __syncthreads();
  size_t wb = ((size_t)(b * 1024 + wh * 32)) * 16384;
  for (int it = 0; it < 13; ++it){
    int id = it * 256 + tid;
    if (id < 3136){                       // 32 ww x 49 px x 2 halves
      int ww = id / 98;
      int rem = id - ww * 98;
      int px = rem >> 1, half = rem & 1;
      short8 v = *(const short8*)(tile + ww * 784 + px * 16 + ((half ^ (px & 1)) << 3));
      int cc = cq * 2 + half;             // global 8-ch chunk 0..31
      int pos = (cc & 24) | ((cc ^ px) & 7);
      *(short8*)(xw + wb + (size_t)ww * 16384 + px * 256 + pos * 8) = v;
    }
  }
}

// ---------------- fused: qkv GEMM + window attention ----------------
// block = 1 window (49 px pad 64), 8 waves = 8 heads, 128 KB LDS (1 block/CU, 2 waves/SIMD)
// __launch_bounds__(512,2): 256-VGPR budget -> no spill of the 96-reg accumulator set
__global__ __launch_bounds__(512, 2) void k_fused(const unsigned short* __restrict__ xw,
                                                  const unsigned short* __restrict__ Wf,
                                                  unsigned short* __restrict__ attnP){
  int bid = blockIdx.x;
  int wg = (bid & 7) * 512 + (bid >> 3);    // 4096 = 8*512, ww-contiguous per XCD
  int b = wg >> 10;
  int win = wg & 1023;
  int wh = win >> 5, ww = win & 31;
  int tid = threadIdx.x;
  int lane = tid & 63;
  int h = tid >> 6;                          // wave = head

  __shared__ __align__(16) unsigned short lds[65536];   // 128 KB

  // ---- phase 0: zero pad rows + DMA 49 window rows from xw ----
  {
    if (tid < 448){                          // rows 50..63
      int rr = 50 + (tid >> 5), ch = tid & 31;
      short8 z = {};
      *(short8*)(lds + 49152 + rr * 256 + ch * 8) = z;
    }
    const unsigned short* xwin = xw + ((size_t)(b * 1024 + wh * 32 + ww)) * 16384;
#pragma unroll
    for (int c3 = 0; c3 < 3; ++c3){
      int k = c3 * 8 + h;                    // chunks 0..23 -> rows 2k, 2k+1
      int row = 2 * k + (lane >> 5);
      GLL16(xwin + row * 256 + (lane & 31) * 8, lds + 49152 + k * 512);
    }
    if (h == 0)                              // chunk 24: row 48 (lanes>=32 dup row48 -> LDS row 49)
      GLL16(xwin + 48 * 256 + (lane & 31) * 8, lds + 49152 + 24 * 512);
  }
  __syncthreads();

  // ---- phase 1: qkv GEMM; W streamed from L2 as B-frags, x from LDS ----
  f32x4 aq[4][2] = {}, ak[4][2] = {}, av[2][4] = {};
  for (int kq = 0; kq < 8; ++kq){
    short8 xf[4];
#pragma unroll
    for (int pt = 0; pt < 4; ++pt){
      int px = pt * 16 + (lane & 15);
      int chk = (kq * 4 + (lane >> 4)) ^ (px & 7);
      xf[pt] = *(const short8*)(lds + 49152 + px * 256 + chk * 8);
    }
    short8 wfr[6];
#pragma unroll
    for (int t = 0; t < 6; ++t)
      wfr[t] = *(const short8*)(Wf + ((size_t)((h * 8 + kq) * 6 + t) * 64 + lane) * 8);
#pragma unroll
    for (int pt = 0; pt < 4; ++pt){
      aq[pt][0] = MFMA16(xf[pt], wfr[0], aq[pt][0]);   // D[px][ch]
      aq[pt][1] = MFMA16(xf[pt], wfr[1], aq[pt][1]);
      ak[pt][0] = MFMA16(xf[pt], wfr[2], ak[pt][0]);
      ak[pt][1] = MFMA16(xf[pt], wfr[3], ak[pt][1]);
      av[0][pt] = MFMA16(wfr[4], xf[pt], av[0][pt]);   // D[ch][px] (transposed v)
      av[1][pt] = MFMA16(wfr[5], xf[pt], av[1][pt]);
    }
  }
  // write q,k -> region A   (D[px][ch]: lane col ch=lane&15, rows px=(lane>>4)*4+j)
#pragma unroll
  for (int pt = 0; pt < 4; ++pt)
#pragma unroll
    for (int t = 0; t < 2; ++t)
#pragma unroll
      for (int j = 0; j < 4; ++j){
        int px = pt * 16 + (lane >> 4) * 4 + j;
        int ch = h * 32 + t * 16 + (lane & 15);
        int pos = px * 256 + (((ch >> 3) ^ (px & 7)) << 3) + (ch & 7);
        lds[pos]         = f2bf(aq[pt][t][j]);
        lds[16384 + pos] = f2bf(ak[pt][t][j]);
      }
  // write vT -> region B   (D[ch][px]: lane col px=lane&15, rows ch=(lane>>4)*4+j)
#pragma unroll
  for (int ct = 0; ct < 2; ++ct)
#pragma unroll
    for (int pt = 0; pt < 4; ++pt)
#pragma unroll
      for (int j = 0; j < 4; ++j){
        int ch = h * 32 + ct * 16 + (lane >> 4) * 4 + j;
        int px = pt * 16 + (lane & 15);
        lds[32768 + ch * 64 + (((px >> 3) ^ (ch & 7)) << 3) + (px & 7)] = f2bf(av[ct][pt][j]);
      }
  __syncthreads();

  // ---- phase 2: S^T = K * Q^T ----
  short8 kf[4], qf[4];
#pragma unroll
  for (int i = 0; i < 4; ++i){
    int px = i * 16 + (lane & 15);
    int chk = (h * 4 + (lane >> 4)) ^ (px & 7);
    qf[i] = *(const short8*)(lds + px * 256 + chk * 8);
    kf[i] = *(const short8*)(lds + 16384 + px * 256 + chk * 8);
  }
  f32x4 s[4][4] = {};
#pragma unroll
  for (int mi = 0; mi < 4; ++mi)
#pragma unroll
    for (int ni = 0; ni < 4; ++ni)
      s[mi][ni] = MFMA16(kf[mi], qf[ni], s[mi][ni]);
  __syncthreads();                 // all q/k reads done; region A becomes sP

  // ---- softmax over k' per q column; write P bf16 to sP (wave-private 8 KB) ----
  const float cexp = 0.25504437f;  // log2(e)/sqrt(32)
  unsigned short* sP = lds + h * 4096;
#pragma unroll
  for (int ni = 0; ni < 4; ++ni){
    float m = -3.0e38f;
#pragma unroll
    for (int mi = 0; mi < 4; ++mi)
#pragma unroll
      for (int r = 0; r < 4; ++r){
        int kp = mi * 16 + ((lane >> 4) * 4) + r;
        if (kp < 49) m = fmaxf(m, s[mi][ni][r]);
      }
    m = fmaxf(m, __shfl_xor(m, 16));
    m = fmaxf(m, __shfl_xor(m, 32));
    float sum = 0.f;
    float pv[4][4];
#pragma unroll
    for (int mi = 0; mi < 4; ++mi)
#pragma unroll
      for (int r = 0; r < 4; ++r){
        int kp = mi * 16 + ((lane >> 4) * 4) + r;
        float e2 = (kp < 49) ? exp2f((s[mi][ni][r] - m) * cexp) : 0.f;
        pv[mi][r] = e2; sum += e2;
      }
    sum += __shfl_xor(sum, 16);
    sum += __shfl_xor(sum, 32);
    float inv = 1.0f / sum;
    int q = ni * 16 + (lane & 15);
#pragma unroll
    for (int mi = 0; mi < 4; ++mi)
#pragma unroll
      for (int r = 0; r < 4; ++r){
        int kp = mi * 16 + ((lane >> 4) * 4) + r;
        int bo = (q * 128 + kp * 2) ^ ((q & 7) << 4);
        sP[bo >> 1] = f2bf(pv[mi][r] * inv);
      }
  }

  // ---- phase 3: O = P * V ----
  f32x4 o[4][2] = {};
#pragma unroll
  for (int kc = 0; kc < 2; ++kc){
    short8 pa[4], vb[2];
#pragma unroll
    for (int mtp = 0; mtp < 4; ++mtp){
      int row = mtp * 16 + (lane & 15);
      int bo = (row * 128 + kc * 64 + (lane >> 4) * 16) ^ ((row & 7) << 4);
      pa[mtp] = *(const short8*)(sP + (bo >> 1));
    }
#pragma unroll
    for (int ntp = 0; ntp < 2; ++ntp){
      int ch = h * 32 + ntp * 16 + (lane & 15);
      int k0 = kc * 32 + (lane >> 4) * 8;
      vb[ntp] = *(const short8*)(lds + 32768 + ch * 64 + (((k0 >> 3) ^ (ch & 7)) << 3));
    }
#pragma unroll
    for (int mtp = 0; mtp < 4; ++mtp)
#pragma unroll
      for (int ntp = 0; ntp < 2; ++ntp)
        o[mtp][ntp] = MFMA16(pa[mtp], vb[ntp], o[mtp][ntp]);
  }
  // O -> region C (x dead since phase-1 barrier)
#pragma unroll
  for (int mtp = 0; mtp < 4; ++mtp)
#pragma unroll
    for (int ntp = 0; ntp < 2; ++ntp)
#pragma unroll
      for (int r = 0; r < 4; ++r){
        int px = mtp * 16 + (lane >> 4) * 4 + r;
        int ch = h * 32 + ntp * 16 + (lane & 15);
        lds[49152 + px * 256 + (((ch >> 3) ^ (px & 7)) << 3) + (ch & 7)] = f2bf(o[mtp][ntp][r]);
      }
  __syncthreads();

  // ---- phase 4: cooperative 16B panel stores ----
  size_t pb0 = (size_t)b * 392 * 4;
#pragma unroll
  for (int it = 0; it < 4; ++it){
    int id = it * 512 + tid;                 // 0..2047 = 64 px * 32 chunks
    int px = id >> 5, ck = id & 31;
    if (px < 49){
      short8 v = *(const short8*)(lds + 49152 + px * 256 + ((ck ^ (px & 7)) << 3));
      int pg = (wh * 7 + px / 7) * 224 + ww * 7 + px % 7;
      int nt = pg >> 7, pr = pg & 127;
      size_t off = (pb0 + (size_t)nt * 4 + (ck >> 3)) * 8192 + panel_off(pr, (ck & 7) * 8);
      *(short8*)(attnP + off) = v;
    }
  }
}

// ---------------- GEMM out + residual (bf16 y) + per-block BN partials ----------------
__global__ __launch_bounds__(256) void k_gemm_out(const unsigned short* __restrict__ Wp,
                                                  const unsigned short* __restrict__ Bp,
                                                  const float* __restrict__ x,
                                                  unsigned short* __restrict__ ybf,
                                                  float* __restrict__ partials){
  int bid = blockIdx.x;
  int wg = (bid & 7) * 392 + (bid >> 3);     // 3136 = 8*392
  int mt = wg & 1; int rest = wg >> 1;       // mt fastest
  int nt = rest % 392; int b = rest / 392;

  __shared__ __align__(16) unsigned short lds[32768];  // dbuf

  int tid = threadIdx.x;
  int lane = tid & 63;
  int wave = tid >> 6;
  int wm = wave >> 1, wn = wave & 1;

  const unsigned short* Apan = Wp + (size_t)mt * 4 * 8192;
  const unsigned short* Bpan = Bp + ((size_t)(b * 392 + nt)) * 4 * 8192;

  int aoff[2][4], boff[2][4];
#pragma unroll
  for (int kk = 0; kk < 2; ++kk)
#pragma unroll
    for (int i = 0; i < 4; ++i){
      int rowA = wm * 64 + i * 16 + (lane & 15);
      aoff[kk][i] = rowA * 64 + (((kk * 4 + (lane >> 4)) ^ (rowA & 7)) << 3);
      int rowB = wn * 64 + i * 16 + (lane & 15);
      boff[kk][i] = rowB * 64 + (((kk * 4 + (lane >> 4)) ^ (rowB & 7)) << 3);
    }
  int cb = wave * 2048;
  f32x4 acc[4][4] = {};

#pragma unroll
  for (int j = 0; j < 4; ++j){
    int o2 = cb + j * 512;
    GLL16(Apan + o2 + lane * 8, lds + o2);
    GLL16(Bpan + o2 + lane * 8, lds + 8192 + o2);
  }
  __syncthreads();

  int cur = 0;
  for (int kq = 0; kq < 4; ++kq){
    if (kq < 3){
      const unsigned short* Ak = Apan + (kq + 1) * 8192;
      const unsigned short* Bk = Bpan + (kq + 1) * 8192;
      unsigned short* dst = lds + (cur ^ 1) * 16384;
#pragma unroll
      for (int j = 0; j < 4; ++j){
        int o2 = cb + j * 512;
        GLL16(Ak + o2 + lane * 8, dst + o2);
        GLL16(Bk + o2 + lane * 8, dst + 8192 + o2);
      }
    }
    const unsigned short* Alds = lds + cur * 16384;
    const unsigned short* Blds = Alds + 8192;
#pragma unroll
    for (int kk = 0; kk < 2; ++kk){
      short8 af[4], bfv[4];
#pragma unroll
      for (int i = 0; i < 4; ++i) af[i]  = *(const short8*)(Alds + aoff[kk][i]);
#pragma unroll
      for (int j = 0; j < 4; ++j) bfv[j] = *(const short8*)(Blds + boff[kk][j]);
#pragma unroll
      for (int i = 0; i < 4; ++i)
#pragma unroll
        for (int j = 0; j < 4; ++j)
          acc[i][j] = MFMA16(af[i], bfv[j], acc[i][j]);
    }
    __syncthreads();
    cur ^= 1;
  }
  // epilogue: residual add, bf16 y store, per-channel partial sums
  float ps[4][4] = {}, pq[4][4] = {};
#pragma unroll
  for (int i = 0; i < 4; ++i)
#pragma unroll
    for (int j = 0; j < 4; ++j){
      int o = mt * 128 + wm * 64 + i * 16 + (lane >> 4) * 4;
      int p = nt * 128 + wn * 64 + j * 16 + (lane & 15);
      size_t base = ((size_t)(b * 256 + o)) * HW_ + p;
#pragma unroll
      for (int r2 = 0; r2 < 4; ++r2){
        float v = acc[i][j][r2] + x[base + (size_t)r2 * HW_];
        ybf[base + (size_t)r2 * HW_] = f2bf(v);
        ps[i][r2] += v;
        pq[i][r2] += v * v;
      }
    }
  float* fl = (float*)lds;    // [wn 2][cl 128] sums, +256 sq
#pragma unroll
  for (int i = 0; i < 4; ++i)
#pragma unroll
    for (int r2 = 0; r2 < 4; ++r2){
      float a = ps[i][r2], q2 = pq[i][r2];
      a += __shfl_xor(a, 1);  q2 += __shfl_xor(q2, 1);
      a += __shfl_xor(a, 2);  q2 += __shfl_xor(q2, 2);
      a += __shfl_xor(a, 4);  q2 += __shfl_xor(q2, 4);
      a += __shfl_xor(a, 8);  q2 += __shfl_xor(q2, 8);
      if ((lane & 15) == 0){
        int cl = wm * 64 + i * 16 + (lane >> 4) * 4 + r2;
        fl[wn * 128 + cl] = a;
        fl[256 + wn * 128 + cl] = q2;
      }
    }
  __syncthreads();
  if (tid < 128){
    partials[(size_t)wg * 256 + tid]       = fl[tid] + fl[128 + tid];
    partials[(size_t)wg * 256 + 128 + tid] = fl[256 + tid] + fl[384 + tid];
  }
}

// ---------------- reduce per-block partials -> mean / rsqrt ----------------
__global__ __launch_bounds__(256) void k_stats2(const float* __restrict__ partials, float* __restrict__ stats){
  int c = blockIdx.x;           // 0..255
  int mt = c >> 7, cl = c & 127;
  int t = threadIdx.x;
  float s = 0.f, q = 0.f;
  for (int idx = t; idx < 1568; idx += 256){
    const float* p = partials + (size_t)(2 * idx + mt) * 256;
    s += p[cl]; q += p[128 + cl];
  }
  __shared__ float r1[256], r2[256];
  r1[t] = s; r2[t] = q; __syncthreads();
  for (int off = 128; off > 0; off >>= 1){
    if (t < off){ r1[t] += r1[t + off]; r2[t] += r2[t + off]; }
    __syncthreads();
  }
  if (t == 0){
    float mean = r1[0] * (1.f / 200704.f);
    float var  = r2[0] * (1.f / 200704.f) - mean * mean;
    stats[c] = mean;
    stats[256 + c] = rsqrtf(var + 1e-5f);
  }
}

// ---------------- normalize: bf16 y -> fp32 out ----------------
__global__ __launch_bounds__(256) void k_norm(const unsigned short* __restrict__ ybf,
                                              const float* __restrict__ stats,
                                              const float* __restrict__ gamma, const float* __restrict__ beta,
                                              float* __restrict__ out){
  const long long total = 6422528LL;   // 51380224 / 8
  for (long long idx = (long long)blockIdx.x * 256 + threadIdx.x; idx < total; idx += (long long)gridDim.x * 256){
    int c = (int)((idx / 6272) & 255);  // 6272 = 50176/8
    float sc = stats[256 + c] * gamma[c];
    float sh = beta[c] - stats[c] * sc;
    short8 v = *(const short8*)(ybf + idx * 8);
    float4 o0, o1;
    o0.x = bf2f((unsigned short)v[0]) * sc + sh;
    o0.y = bf2f((unsigned short)v[1]) * sc + sh;
    o0.z = bf2f((unsigned short)v[2]) * sc + sh;
    o0.w = bf2f((unsigned short)v[3]) * sc + sh;
    o1.x = bf2f((unsigned short)v[4]) * sc + sh;
    o1.y = bf2f((unsigned short)v[5]) * sc + sh;
    o1.z = bf2f((unsigned short)v[6]) * sc + sh;
    o1.w = bf2f((unsigned short)v[7]) * sc + sh;
    *(float4*)(out + idx * 8)     = o0;
    *(float4*)(out + idx * 8 + 4) = o1;
  }
}

extern "C" void kernel_launch(void* const* d_in, const int* in_sizes, int n_in,
                              void* d_out, int out_size, void* d_ws, size_t ws_size,
                              hipStream_t stream){
  const float* x     = (const float*)d_in[0];
  const float* Wq    = (const float*)d_in[1];
  const float* Wk    = (const float*)d_in[2];
  const float* Wv    = (const float*)d_in[3];
  const float* Wo    = (const float*)d_in[4];
  const float* gamma = (const float*)d_in[5];
  const float* beta  = (const float*)d_in[6];
  float* out = (float*)d_out;

  char* ws = (char*)d_ws;
  unsigned short* Wf     = (unsigned short*)ws;                               // 393216 B
  unsigned short* Wo_b   = (unsigned short*)(ws + 393216);                    // 131072 B
  float*          stats  = (float*)(ws + 524288);                             // 2048 B
  unsigned short* xw     = (unsigned short*)(ws + 1048576);                   // 134217728 B
  unsigned short* attnP  = (unsigned short*)(ws + 1048576 + 134217728);       // 102760448 B
  float*          partials = (float*)(ws + 1048576 + 134217728 + 102760448);  // 3211264 B
  unsigned short* ybf    = xw;   // alias: xw dead after k_fused (stream-ordered)

  k_convw<<<128, 256, 0, stream>>>(Wq, Wk, Wv, Wo, Wf, Wo_b);
  k_xw<<<2048, 256, 0, stream>>>(x, xw);
  k_fused<<<4096, 512, 0, stream>>>(xw, Wf, attnP);
  k_gemm_out<<<3136, 256, 0, stream>>>(Wo_b, attnP, x, ybf, partials);
  k_stats2<<<256, 256, 0, stream>>>(partials, stats);
  k_norm<<<4096, 256, 0, stream>>>(ybf, stats, gamma, beta, out);
}

// Round 9
// 487.264 us; speedup vs baseline: 1.0708x; 1.0324x over previous
//
#include <hip/hip_runtime.h>
#include <stdint.h>

typedef __attribute__((ext_vector_type(8))) short short8;
typedef __attribute__((ext_vector_type(4))) float f32x4;

#define MFMA16(a,b,c) __builtin_amdgcn_mfma_f32_16x16x32_bf16((a),(b),(c),0,0,0)

// async global->LDS DMA, 16B per lane; LDS dest = wave-uniform base + lane*16B
#define GLL16(g, l) __builtin_amdgcn_global_load_lds( \
    (const __attribute__((address_space(1))) void*)(g), \
    (__attribute__((address_space(3))) void*)(l), 16, 0, 0)

__device__ __forceinline__ unsigned short f2bf(float f){
  unsigned u = __builtin_bit_cast(unsigned, f);
  u += 0x7fffu + ((u >> 16) & 1u);
  return (unsigned short)(u >> 16);
}
__device__ __forceinline__ float bf2f(unsigned short s){
  unsigned u = ((unsigned)s) << 16;
  return __builtin_bit_cast(float, u);
}

static constexpr int HW_ = 50176;   // 224*224

// offset of element (row r 0..127, k c64 0..63) inside one 8192-elem panel,
// XOR-swizzled so ds_read_b128 of a 16-lane column slice is conflict-free
__device__ __forceinline__ int panel_off(int r, int c64){
  return r * 64 + ((((c64 >> 3) ^ (r & 7))) << 3) + (c64 & 7);
}

// ---------------- weights fp32 -> bf16 ----------------
__global__ __launch_bounds__(256) void k_convw(const float* __restrict__ Wq, const float* __restrict__ Wk,
                        const float* __restrict__ Wv, const float* __restrict__ Wo,
                        unsigned short* __restrict__ Wf, unsigned short* __restrict__ Wob){
  int gid = blockIdx.x * 256 + threadIdx.x;   // grid 128 -> 32768
  if (gid < 24576){
    int lane = gid & 63;
    int r1 = gid >> 6;          // 0..383
    int t = r1 % 6;
    int r2 = r1 / 6;            // 0..63
    int kq = r2 & 7, hh = r2 >> 3;
    const float* W = (t < 2) ? Wq : (t < 4) ? Wk : Wv;
    int ch = hh * 32 + (t & 1) * 16 + (lane & 15);
    int k0 = kq * 32 + (lane >> 4) * 8;
    const float* src = W + ch * 256 + k0;
    float4 a = *(const float4*)src, b2 = *(const float4*)(src + 4);
    short8 v;
    v[0]=f2bf(a.x); v[1]=f2bf(a.y); v[2]=f2bf(a.z); v[3]=f2bf(a.w);
    v[4]=f2bf(b2.x); v[5]=f2bf(b2.y); v[6]=f2bf(b2.z); v[7]=f2bf(b2.w);
    *(short8*)(Wf + (size_t)gid * 8) = v;
  } else {
    int og = gid - 24576;       // 0..8191
    int o = og >> 5, ck = og & 31;
    const float* src = Wo + o * 256 + ck * 8;
    float4 a = *(const float4*)src, b2 = *(const float4*)(src + 4);
    short8 v;
    v[0]=f2bf(a.x); v[1]=f2bf(a.y); v[2]=f2bf(a.z); v[3]=f2bf(a.w);
    v[4]=f2bf(b2.x); v[5]=f2bf(b2.y); v[6]=f2bf(b2.z); v[7]=f2bf(b2.w);
    int kq = ck >> 3;
    int off = panel_off(o & 127, (ck & 7) * 8);
    *(short8*)(Wob + ((o >> 7) * 4 + kq) * 8192 + off) = v;
  }
}

// ---------------- x (B,C,H,W) f32 -> xw[win][half 2][px 49/64][128c swz] bf16 ----------------
__global__ __launch_bounds__(256) void k_xw(const float* __restrict__ x, unsigned short* __restrict__ xw){
  int bid = blockIdx.x;
  int cq = bid & 15, wh = (bid >> 4) & 31, b = bid >> 9;
  __shared__ __align__(16) unsigned short tile[25088];  // 49 KB
  int tid = threadIdx.x;
  for (int it = 0; it < 25; ++it){
    int idx = it * 256 + tid;
    if (idx < 6272){
      int c = idx & 15;
      int t2 = idx >> 4;                  // 0..391
      int r = t2 / 56;
      int w4 = t2 % 56;
      float4 v = *(const float4*)(x + ((size_t)(b * 256 + cq * 16 + c)) * HW_ + (wh * 7 + r) * 224 + w4 * 4);
      float vv[4] = {v.x, v.y, v.z, v.w};
      int w0 = w4 * 4;
      int ww = w0 / 7;
      int cl = w0 % 7;
#pragma unroll
      for (int i = 0; i < 4; ++i){
        int px = r * 7 + cl;
        tile[ww * 784 + px * 16 + (((c >> 3) ^ (px & 1)) << 3) + (c & 7)] = f2bf(vv[i]);
        if (++cl == 7){ cl = 0; ++ww; }
      }
    }
  }
  __syncthreads();
  size_t wb = ((size_t)(b * 1024 + wh * 32)) * 16384;
  for (int it = 0; it < 13; ++it){
    int id = it * 256 + tid;
    if (id < 3136){                       // 32 ww x 49 px x 2 chunk-slots
      int ww = id / 98;
      int rem = id - ww * 98;
      int px = rem >> 1, hb = rem & 1;
      short8 v = *(const short8*)(tile + ww * 784 + px * 16 + ((hb ^ (px & 1)) << 3));
      int cc = cq * 2 + hb;               // global 8-ch chunk 0..31
      int half = cc >> 4, c4 = cc & 15;
      int pos = (c4 & 8) | ((c4 ^ px) & 7);
      *(short8*)(xw + wb + (size_t)ww * 16384 + half * 8192 + px * 128 + pos * 8) = v;
    }
  }
}

// ---------------- fused: qkv GEMM + window attention ----------------
// block = (window, 4-head half), 4 waves = 4 heads, 48 KB LDS -> 3 blocks/CU
// LDS elems (u16): [0,8192) x-half [64px][128c swz] (later vT [128ch][64px]);
//                  [8192,16384) q [64px][128ch swz]; [16384,24576) k (same)
//                  post-ph2: sP wave hl at 8192+hl*4096; O in own sP
__global__ __launch_bounds__(256, 3) void k_fused(const unsigned short* __restrict__ xw,
                                                  const unsigned short* __restrict__ Wf,
                                                  unsigned short* __restrict__ attnP){
  int bid = blockIdx.x;
  int wg = (bid & 7) * 1024 + (bid >> 3);   // 8192 = 8*1024; window pair on same XCD
  int hh = wg & 1; int win = wg >> 1;
  int b = win >> 10;
  int wh = (win >> 5) & 31, ww = win & 31;
  int tid = threadIdx.x;
  int lane = tid & 63;
  int hl = tid >> 6;                         // local head 0..3
  int hg = hh * 4 + hl;                      // global head

  __shared__ __align__(16) unsigned short lds[24576];   // 48 KB

  const unsigned short* xwin = xw + (size_t)win * 16384;

  // ---- phase 0: zero pad rows 49..63 + DMA half0 (px 0..48) ----
  if (tid < 240){
    int rr = 49 + (tid >> 4), ck = tid & 15;
    short8 z = {};
    *(short8*)(lds + rr * 128 + ck * 8) = z;
  }
#pragma unroll
  for (int it = 0; it < 4; ++it){
    int chunk = it * 256 + tid;              // 16 chunks per px row
    if (chunk < 784) GLL16(xwin + chunk * 8, lds + chunk * 8);
  }
  __syncthreads();

  // ---- phase 1: qkv GEMM over 2 ch-halves; W streamed from L2 ----
  f32x4 aq[4][2] = {}, ak[4][2] = {}, av[2][4] = {};
  for (int half = 0; half < 2; ++half){
    for (int kq = 0; kq < 4; ++kq){
      short8 xf[4];
#pragma unroll
      for (int pt = 0; pt < 4; ++pt){
        int px = pt * 16 + (lane & 15);
        int c = kq * 4 + (lane >> 4);        // chunk 0..15
        int cs = (c & 8) | ((c ^ px) & 7);
        xf[pt] = *(const short8*)(lds + px * 128 + cs * 8);
      }
      short8 wfr[6];
      int kqg = half * 4 + kq;
#pragma unroll
      for (int t = 0; t < 6; ++t)
        wfr[t] = *(const short8*)(Wf + ((size_t)((hg * 8 + kqg) * 6 + t) * 64 + lane) * 8);
#pragma unroll
      for (int pt = 0; pt < 4; ++pt){
        aq[pt][0] = MFMA16(xf[pt], wfr[0], aq[pt][0]);   // D[px][ch]
        aq[pt][1] = MFMA16(xf[pt], wfr[1], aq[pt][1]);
        ak[pt][0] = MFMA16(xf[pt], wfr[2], ak[pt][0]);
        ak[pt][1] = MFMA16(xf[pt], wfr[3], ak[pt][1]);
        av[0][pt] = MFMA16(wfr[4], xf[pt], av[0][pt]);   // D[ch][px] (transposed v)
        av[1][pt] = MFMA16(wfr[5], xf[pt], av[1][pt]);
      }
    }
    if (half == 0){
      __syncthreads();                       // all half0 x reads done
#pragma unroll
      for (int it = 0; it < 4; ++it){
        int chunk = it * 256 + tid;
        if (chunk < 784) GLL16(xwin + 8192 + chunk * 8, lds + chunk * 8);
      }
      __syncthreads();                       // half1 landed
    }
  }

  // write q,k (wave-private read-back; region shared for sP later)
#pragma unroll
  for (int pt = 0; pt < 4; ++pt)
#pragma unroll
    for (int t = 0; t < 2; ++t)
#pragma unroll
      for (int j = 0; j < 4; ++j){
        int px = pt * 16 + (lane >> 4) * 4 + j;
        int chl = hl * 32 + t * 16 + (lane & 15);   // 0..127
        int ck = chl >> 3;
        int pos = px * 128 + (((ck & 8) | ((ck ^ px) & 7)) << 3) + (chl & 7);
        lds[8192 + pos]  = f2bf(aq[pt][t][j]);
        lds[16384 + pos] = f2bf(ak[pt][t][j]);
      }
  __syncthreads();                           // all ph1 x reads done -> x region becomes vT
  // write vT -> x region [128ch][64px swz]
#pragma unroll
  for (int ct = 0; ct < 2; ++ct)
#pragma unroll
    for (int pt = 0; pt < 4; ++pt)
#pragma unroll
      for (int j = 0; j < 4; ++j){
        int chl = hl * 32 + ct * 16 + (lane >> 4) * 4 + j;
        int px = pt * 16 + (lane & 15);
        lds[chl * 64 + (((px >> 3) ^ (chl & 7)) << 3) + (px & 7)] = f2bf(av[ct][pt][j]);
      }

  // ---- phase 2: S^T = K * Q^T (own head's q,k) ----
  short8 kf[4], qf[4];
#pragma unroll
  for (int i = 0; i < 4; ++i){
    int px = i * 16 + (lane & 15);
    int c = hl * 4 + (lane >> 4);            // own head's chunks
    int cs = (c & 8) | ((c ^ px) & 7);
    qf[i] = *(const short8*)(lds + 8192 + px * 128 + cs * 8);
    kf[i] = *(const short8*)(lds + 16384 + px * 128 + cs * 8);
  }
  f32x4 s[4][4] = {};
#pragma unroll
  for (int mi = 0; mi < 4; ++mi)
#pragma unroll
    for (int ni = 0; ni < 4; ++ni)
      s[mi][ni] = MFMA16(kf[mi], qf[ni], s[mi][ni]);
  __syncthreads();                           // all q/k reads done; q+k region becomes sP

  // ---- softmax over k' per q column; write P bf16 to own sP ----
  const float cexp = 0.25504437f;            // log2(e)/sqrt(32)
  unsigned short* sP = lds + 8192 + hl * 4096;
#pragma unroll
  for (int ni = 0; ni < 4; ++ni){
    float m = -3.0e38f;
#pragma unroll
    for (int mi = 0; mi < 4; ++mi)
#pragma unroll
      for (int r = 0; r < 4; ++r){
        int kp = mi * 16 + ((lane >> 4) * 4) + r;
        if (kp < 49) m = fmaxf(m, s[mi][ni][r]);
      }
    m = fmaxf(m, __shfl_xor(m, 16));
    m = fmaxf(m, __shfl_xor(m, 32));
    float sum = 0.f;
    float pv[4][4];
#pragma unroll
    for (int mi = 0; mi < 4; ++mi)
#pragma unroll
      for (int r = 0; r < 4; ++r){
        int kp = mi * 16 + ((lane >> 4) * 4) + r;
        float e2 = (kp < 49) ? exp2f((s[mi][ni][r] - m) * cexp) : 0.f;
        pv[mi][r] = e2; sum += e2;
      }
    sum += __shfl_xor(sum, 16);
    sum += __shfl_xor(sum, 32);
    float inv = 1.0f / sum;
    int q = ni * 16 + (lane & 15);
#pragma unroll
    for (int mi = 0; mi < 4; ++mi)
#pragma unroll
      for (int r = 0; r < 4; ++r){
        int kp = mi * 16 + ((lane >> 4) * 4) + r;
        int bo = (q * 128 + kp * 2) ^ ((q & 7) << 4);
        sP[bo >> 1] = f2bf(pv[mi][r] * inv);
      }
  }

  // ---- phase 3: O = P * V (own sP + own vT rows) ----
  f32x4 o[4][2] = {};
#pragma unroll
  for (int kc = 0; kc < 2; ++kc){
    short8 pa[4], vb[2];
#pragma unroll
    for (int mtp = 0; mtp < 4; ++mtp){
      int row = mtp * 16 + (lane & 15);
      int bo = (row * 128 + kc * 64 + (lane >> 4) * 16) ^ ((row & 7) << 4);
      pa[mtp] = *(const short8*)(sP + (bo >> 1));
    }
#pragma unroll
    for (int ntp = 0; ntp < 2; ++ntp){
      int chl = hl * 32 + ntp * 16 + (lane & 15);
      int k0 = kc * 32 + (lane >> 4) * 8;
      vb[ntp] = *(const short8*)(lds + chl * 64 + (((k0 >> 3) ^ (chl & 7)) << 3));
    }
#pragma unroll
    for (int mtp = 0; mtp < 4; ++mtp)
#pragma unroll
      for (int ntp = 0; ntp < 2; ++ntp)
        o[mtp][ntp] = MFMA16(pa[mtp], vb[ntp], o[mtp][ntp]);
  }
  // O -> own sP area [64px][32ch swz] (wave-private, after own pa reads)
#pragma unroll
  for (int mtp = 0; mtp < 4; ++mtp)
#pragma unroll
    for (int ntp = 0; ntp < 2; ++ntp)
#pragma unroll
      for (int r = 0; r < 4; ++r){
        int px = mtp * 16 + (lane >> 4) * 4 + r;
        int ch5 = ntp * 16 + (lane & 15);    // 0..31
        int c2 = ch5 >> 3;
        sP[px * 32 + (((c2 ^ px) & 3) << 3) + (ch5 & 7)] = f2bf(o[mtp][ntp][r]);
      }
  __syncthreads();

  // ---- phase 4: cooperative 16B panel stores (this block's 4 heads) ----
  size_t pb0 = (size_t)b * 392 * 4;
#pragma unroll
  for (int it = 0; it < 4; ++it){
    int id = it * 256 + tid;                 // 0..1023 = 64px * 16 chunks
    int px = id >> 4, ck = id & 15;
    if (px < 49){
      int hl2 = ck >> 2, c2 = ck & 3;
      short8 v = *(const short8*)(lds + 8192 + hl2 * 4096 + px * 32 + (((c2 ^ px) & 3) << 3));
      int ch0 = (hh * 4 + hl2) * 32 + c2 * 8;
      int pg = (wh * 7 + px / 7) * 224 + ww * 7 + px % 7;
      int nt = pg >> 7, pr = pg & 127;
      size_t off = (pb0 + (size_t)nt * 4 + (ch0 >> 6)) * 8192 + panel_off(pr, ch0 & 63);
      *(short8*)(attnP + off) = v;
    }
  }
}

// ---------------- GEMM out + residual (bf16 y) + per-block BN partials ----------------
__global__ __launch_bounds__(256) void k_gemm_out(const unsigned short* __restrict__ Wp,
                                                  const unsigned short* __restrict__ Bp,
                                                  const float* __restrict__ x,
                                                  unsigned short* __restrict__ ybf,
                                                  float* __restrict__ partials){
  int bid = blockIdx.x;
  int wg = (bid & 7) * 392 + (bid >> 3);     // 3136 = 8*392
  int mt = wg & 1; int rest = wg >> 1;       // mt fastest
  int nt = rest % 392; int b = rest / 392;

  __shared__ __align__(16) unsigned short lds[32768];  // dbuf

  int tid = threadIdx.x;
  int lane = tid & 63;
  int wave = tid >> 6;
  int wm = wave >> 1, wn = wave & 1;

  const unsigned short* Apan = Wp + (size_t)mt * 4 * 8192;
  const unsigned short* Bpan = Bp + ((size_t)(b * 392 + nt)) * 4 * 8192;

  int aoff[2][4], boff[2][4];
#pragma unroll
  for (int kk = 0; kk < 2; ++kk)
#pragma unroll
    for (int i = 0; i < 4; ++i){
      int rowA = wm * 64 + i * 16 + (lane & 15);
      aoff[kk][i] = rowA * 64 + (((kk * 4 + (lane >> 4)) ^ (rowA & 7)) << 3);
      int rowB = wn * 64 + i * 16 + (lane & 15);
      boff[kk][i] = rowB * 64 + (((kk * 4 + (lane >> 4)) ^ (rowB & 7)) << 3);
    }
  int cb = wave * 2048;
  f32x4 acc[4][4] = {};

#pragma unroll
  for (int j = 0; j < 4; ++j){
    int o2 = cb + j * 512;
    GLL16(Apan + o2 + lane * 8, lds + o2);
    GLL16(Bpan + o2 + lane * 8, lds + 8192 + o2);
  }
  __syncthreads();

  int cur = 0;
  for (int kq = 0; kq < 4; ++kq){
    if (kq < 3){
      const unsigned short* Ak = Apan + (kq + 1) * 8192;
      const unsigned short* Bk = Bpan + (kq + 1) * 8192;
      unsigned short* dst = lds + (cur ^ 1) * 16384;
#pragma unroll
      for (int j = 0; j < 4; ++j){
        int o2 = cb + j * 512;
        GLL16(Ak + o2 + lane * 8, dst + o2);
        GLL16(Bk + o2 + lane * 8, dst + 8192 + o2);
      }
    }
    const unsigned short* Alds = lds + cur * 16384;
    const unsigned short* Blds = Alds + 8192;
#pragma unroll
    for (int kk = 0; kk < 2; ++kk){
      short8 af[4], bfv[4];
#pragma unroll
      for (int i = 0; i < 4; ++i) af[i]  = *(const short8*)(Alds + aoff[kk][i]);
#pragma unroll
      for (int j = 0; j < 4; ++j) bfv[j] = *(const short8*)(Blds + boff[kk][j]);
#pragma unroll
      for (int i = 0; i < 4; ++i)
#pragma unroll
        for (int j = 0; j < 4; ++j)
          acc[i][j] = MFMA16(af[i], bfv[j], acc[i][j]);
    }
    __syncthreads();
    cur ^= 1;
  }
  // epilogue: residual add, bf16 y store, per-channel partial sums
  float ps[4][4] = {}, pq[4][4] = {};
#pragma unroll
  for (int i = 0; i < 4; ++i)
#pragma unroll
    for (int j = 0; j < 4; ++j){
      int o = mt * 128 + wm * 64 + i * 16 + (lane >> 4) * 4;
      int p = nt * 128 + wn * 64 + j * 16 + (lane & 15);
      size_t base = ((size_t)(b * 256 + o)) * HW_ + p;
#pragma unroll
      for (int r2 = 0; r2 < 4; ++r2){
        float v = acc[i][j][r2] + x[base + (size_t)r2 * HW_];
        ybf[base + (size_t)r2 * HW_] = f2bf(v);
        ps[i][r2] += v;
        pq[i][r2] += v * v;
      }
    }
  float* fl = (float*)lds;    // [wn 2][cl 128] sums, +256 sq
#pragma unroll
  for (int i = 0; i < 4; ++i)
#pragma unroll
    for (int r2 = 0; r2 < 4; ++r2){
      float a = ps[i][r2], q2 = pq[i][r2];
      a += __shfl_xor(a, 1);  q2 += __shfl_xor(q2, 1);
      a += __shfl_xor(a, 2);  q2 += __shfl_xor(q2, 2);
      a += __shfl_xor(a, 4);  q2 += __shfl_xor(q2, 4);
      a += __shfl_xor(a, 8);  q2 += __shfl_xor(q2, 8);
      if ((lane & 15) == 0){
        int cl = wm * 64 + i * 16 + (lane >> 4) * 4 + r2;
        fl[wn * 128 + cl] = a;
        fl[256 + wn * 128 + cl] = q2;
      }
    }
  __syncthreads();
  if (tid < 128){
    partials[(size_t)wg * 256 + tid]       = fl[tid] + fl[128 + tid];
    partials[(size_t)wg * 256 + 128 + tid] = fl[256 + tid] + fl[384 + tid];
  }
}

// ---------------- reduce per-block partials -> mean / rsqrt ----------------
__global__ __launch_bounds__(256) void k_stats2(const float* __restrict__ partials, float* __restrict__ stats){
  int c = blockIdx.x;           // 0..255
  int mt = c >> 7, cl = c & 127;
  int t = threadIdx.x;
  float s = 0.f, q = 0.f;
  for (int idx = t; idx < 1568; idx += 256){
    const float* p = partials + (size_t)(2 * idx + mt) * 256;
    s += p[cl]; q += p[128 + cl];
  }
  __shared__ float r1[256], r2[256];
  r1[t] = s; r2[t] = q; __syncthreads();
  for (int off = 128; off > 0; off >>= 1){
    if (t < off){ r1[t] += r1[t + off]; r2[t] += r2[t + off]; }
    __syncthreads();
  }
  if (t == 0){
    float mean = r1[0] * (1.f / 200704.f);
    float var  = r2[0] * (1.f / 200704.f) - mean * mean;
    stats[c] = mean;
    stats[256 + c] = rsqrtf(var + 1e-5f);
  }
}

// ---------------- normalize: bf16 y -> fp32 out ----------------
__global__ __launch_bounds__(256) void k_norm(const unsigned short* __restrict__ ybf,
                                              const float* __restrict__ stats,
                                              const float* __restrict__ gamma, const float* __restrict__ beta,
                                              float* __restrict__ out){
  const long long total = 6422528LL;   // 51380224 / 8
  for (long long idx = (long long)blockIdx.x * 256 + threadIdx.x; idx < total; idx += (long long)gridDim.x * 256){
    int c = (int)((idx / 6272) & 255);  // 6272 = 50176/8
    float sc = stats[256 + c] * gamma[c];
    float sh = beta[c] - stats[c] * sc;
    short8 v = *(const short8*)(ybf + idx * 8);
    float4 o0, o1;
    o0.x = bf2f((unsigned short)v[0]) * sc + sh;
    o0.y = bf2f((unsigned short)v[1]) * sc + sh;
    o0.z = bf2f((unsigned short)v[2]) * sc + sh;
    o0.w = bf2f((unsigned short)v[3]) * sc + sh;
    o1.x = bf2f((unsigned short)v[4]) * sc + sh;
    o1.y = bf2f((unsigned short)v[5]) * sc + sh;
    o1.z = bf2f((unsigned short)v[6]) * sc + sh;
    o1.w = bf2f((unsigned short)v[7]) * sc + sh;
    *(float4*)(out + idx * 8)     = o0;
    *(float4*)(out + idx * 8 + 4) = o1;
  }
}

extern "C" void kernel_launch(void* const* d_in, const int* in_sizes, int n_in,
                              void* d_out, int out_size, void* d_ws, size_t ws_size,
                              hipStream_t stream){
  const float* x     = (const float*)d_in[0];
  const float* Wq    = (const float*)d_in[1];
  const float* Wk    = (const float*)d_in[2];
  const float* Wv    = (const float*)d_in[3];
  const float* Wo    = (const float*)d_in[4];
  const float* gamma = (const float*)d_in[5];
  const float* beta  = (const float*)d_in[6];
  float* out = (float*)d_out;

  char* ws = (char*)d_ws;
  unsigned short* Wf     = (unsigned short*)ws;                               // 393216 B
  unsigned short* Wo_b   = (unsigned short*)(ws + 393216);                    // 131072 B
  float*          stats  = (float*)(ws + 524288);                             // 2048 B
  unsigned short* xw     = (unsigned short*)(ws + 1048576);                   // 134217728 B
  unsigned short* attnP  = (unsigned short*)(ws + 1048576 + 134217728);       // 102760448 B
  float*          partials = (float*)(ws + 1048576 + 134217728 + 102760448);  // 3211264 B
  unsigned short* ybf    = xw;   // alias: xw dead after k_fused (stream-ordered)

  k_convw<<<128, 256, 0, stream>>>(Wq, Wk, Wv, Wo, Wf, Wo_b);
  k_xw<<<2048, 256, 0, stream>>>(x, xw);
  k_fused<<<8192, 256, 0, stream>>>(xw, Wf, attnP);
  k_gemm_out<<<3136, 256, 0, stream>>>(Wo_b, attnP, x, ybf, partials);
  k_stats2<<<256, 256, 0, stream>>>(partials, stats);
  k_norm<<<4096, 256, 0, stream>>>(ybf, stats, gamma, beta, out);
}

// Round 11
// 470.770 us; speedup vs baseline: 1.1083x; 1.0350x over previous
//
#include <hip/hip_runtime.h>
#include <stdint.h>

typedef __attribute__((ext_vector_type(8))) short short8;
typedef __attribute__((ext_vector_type(4))) float f32x4;

#define MFMA16(a,b,c) __builtin_amdgcn_mfma_f32_16x16x32_bf16((a),(b),(c),0,0,0)

// async global->LDS DMA, 16B per lane; LDS dest = wave-uniform base + lane*16B
#define GLL16(g, l) __builtin_amdgcn_global_load_lds( \
    (const __attribute__((address_space(1))) void*)(g), \
    (__attribute__((address_space(3))) void*)(l), 16, 0, 0)

__device__ __forceinline__ unsigned short f2bf(float f){
  unsigned u = __builtin_bit_cast(unsigned, f);
  u += 0x7fffu + ((u >> 16) & 1u);
  return (unsigned short)(u >> 16);
}
__device__ __forceinline__ float bf2f(unsigned short s){
  unsigned u = ((unsigned)s) << 16;
  return __builtin_bit_cast(float, u);
}
// pack 4 f32 -> 4 bf16 in a u64 (RNE, proven f2bf path)
__device__ __forceinline__ unsigned long long pack4(f32x4 v){
  return (unsigned long long)f2bf(v[0])
       | ((unsigned long long)f2bf(v[1]) << 16)
       | ((unsigned long long)f2bf(v[2]) << 32)
       | ((unsigned long long)f2bf(v[3]) << 48);
}

static constexpr int HW_ = 50176;   // 224*224

// offset of element (row r 0..127, k c64 0..63) inside one 8192-elem panel,
// XOR-swizzled so ds_read_b128 of a 16-lane column slice is conflict-free
__device__ __forceinline__ int panel_off(int r, int c64){
  return r * 64 + ((((c64 >> 3) ^ (r & 7))) << 3) + (c64 & 7);
}

// ---------------- weights fp32 -> bf16 ----------------
__global__ __launch_bounds__(256) void k_convw(const float* __restrict__ Wq, const float* __restrict__ Wk,
                        const float* __restrict__ Wv, const float* __restrict__ Wo,
                        unsigned short* __restrict__ Wf, unsigned short* __restrict__ Wob){
  int gid = blockIdx.x * 256 + threadIdx.x;   // grid 128 -> 32768
  if (gid < 24576){
    int lane = gid & 63;
    int r1 = gid >> 6;          // 0..383
    int t = r1 % 6;
    int r2 = r1 / 6;            // 0..63
    int kq = r2 & 7, hh = r2 >> 3;
    const float* W = (t < 2) ? Wq : (t < 4) ? Wk : Wv;
    int ch = hh * 32 + (t & 1) * 16 + (lane & 15);
    int k0 = kq * 32 + (lane >> 4) * 8;
    const float* src = W + ch * 256 + k0;
    float4 a = *(const float4*)src, b2 = *(const float4*)(src + 4);
    short8 v;
    v[0]=f2bf(a.x); v[1]=f2bf(a.y); v[2]=f2bf(a.z); v[3]=f2bf(a.w);
    v[4]=f2bf(b2.x); v[5]=f2bf(b2.y); v[6]=f2bf(b2.z); v[7]=f2bf(b2.w);
    *(short8*)(Wf + (size_t)gid * 8) = v;
  } else {
    int og = gid - 24576;       // 0..8191
    int o = og >> 5, ck = og & 31;
    const float* src = Wo + o * 256 + ck * 8;
    float4 a = *(const float4*)src, b2 = *(const float4*)(src + 4);
    short8 v;
    v[0]=f2bf(a.x); v[1]=f2bf(a.y); v[2]=f2bf(a.z); v[3]=f2bf(a.w);
    v[4]=f2bf(b2.x); v[5]=f2bf(b2.y); v[6]=f2bf(b2.z); v[7]=f2bf(b2.w);
    int kq = ck >> 3;
    int off = panel_off(o & 127, (ck & 7) * 8);
    *(short8*)(Wob + ((o >> 7) * 4 + kq) * 8192 + off) = v;
  }
}

// ---------------- x (B,C,H,W) f32 -> xw[win][half 2][px 49/64][128c swz] bf16 ----------------
__global__ __launch_bounds__(256) void k_xw(const float* __restrict__ x, unsigned short* __restrict__ xw){
  int bid = blockIdx.x;
  int cq = bid & 15, wh = (bid >> 4) & 31, b = bid >> 9;
  __shared__ __align__(16) unsigned short tile[25088];  // 49 KB
  int tid = threadIdx.x;
  for (int it = 0; it < 25; ++it){
    int idx = it * 256 + tid;
    if (idx < 6272){
      int c = idx & 15;
      int t2 = idx >> 4;                  // 0..391
      int r = t2 / 56;
      int w4 = t2 % 56;
      float4 v = *(const float4*)(x + ((size_t)(b * 256 + cq * 16 + c)) * HW_ + (wh * 7 + r) * 224 + w4 * 4);
      float vv[4] = {v.x, v.y, v.z, v.w};
      int w0 = w4 * 4;
      int ww = w0 / 7;
      int cl = w0 % 7;
#pragma unroll
      for (int i = 0; i < 4; ++i){
        int px = r * 7 + cl;
        tile[ww * 784 + px * 16 + (((c >> 3) ^ (px & 1)) << 3) + (c & 7)] = f2bf(vv[i]);
        if (++cl == 7){ cl = 0; ++ww; }
      }
    }
  }
  __syncthreads();
  size_t wb = ((size_t)(b * 1024 + wh * 32)) * 16384;
  for (int it = 0; it < 13; ++it){
    int id = it * 256 + tid;
    if (id < 3136){                       // 32 ww x 49 px x 2 chunk-slots
      int ww = id / 98;
      int rem = id - ww * 98;
      int px = rem >> 1, hb = rem & 1;
      short8 v = *(const short8*)(tile + ww * 784 + px * 16 + ((hb ^ (px & 1)) << 3));
      int cc = cq * 2 + hb;               // global 8-ch chunk 0..31
      int half = cc >> 4, c4 = cc & 15;
      int pos = (c4 & 8) | ((c4 ^ px) & 7);
      *(short8*)(xw + wb + (size_t)ww * 16384 + half * 8192 + px * 128 + pos * 8) = v;
    }
  }
}

// ---------------- fused: qkv GEMM + window attention ----------------
// block = (window, 4-head half), 4 waves = 4 heads, 48 KB LDS -> 3 blocks/CU
// All LDS writebacks b64-packed via operand-order choice (f2bf packing)
__global__ __launch_bounds__(256, 3) void k_fused(const unsigned short* __restrict__ xw,
                                                  const unsigned short* __restrict__ Wf,
                                                  unsigned short* __restrict__ attnP){
  int bid = blockIdx.x;
  int wg = (bid & 7) * 1024 + (bid >> 3);   // 8192 = 8*1024; window pair on same XCD
  int hh = wg & 1; int win = wg >> 1;
  int b = win >> 10;
  int wh = (win >> 5) & 31, ww = win & 31;
  int tid = threadIdx.x;
  int lane = tid & 63;
  int hl = tid >> 6;                         // local head 0..3
  int hg = hh * 4 + hl;                      // global head

  __shared__ __align__(16) unsigned short lds[24576];   // 48 KB

  const unsigned short* xwin = xw + (size_t)win * 16384;

  // ---- phase 0: zero pad rows 49..63 + DMA half0 (px 0..48) ----
  if (tid < 240){
    int rr = 49 + (tid >> 4), ck = tid & 15;
    short8 z = {};
    *(short8*)(lds + rr * 128 + ck * 8) = z;
  }
#pragma unroll
  for (int it = 0; it < 4; ++it){
    int chunk = it * 256 + tid;              // 16 chunks per px row
    if (chunk < 784) GLL16(xwin + chunk * 8, lds + chunk * 8);
  }
  __syncthreads();

  // ---- phase 1: qkv GEMM; q,k transposed (D[ch][px]); v natural (D[px][ch]) ----
  f32x4 aqT[2][4] = {}, akT[2][4] = {}, avN[4][2] = {};
  for (int half = 0; half < 2; ++half){
    for (int kq = 0; kq < 4; ++kq){
      short8 xf[4];
#pragma unroll
      for (int pt = 0; pt < 4; ++pt){
        int px = pt * 16 + (lane & 15);
        int c = kq * 4 + (lane >> 4);        // chunk 0..15
        int cs = (c & 8) | ((c ^ px) & 7);
        xf[pt] = *(const short8*)(lds + px * 128 + cs * 8);
      }
      short8 wfr[6];
      int kqg = half * 4 + kq;
#pragma unroll
      for (int t = 0; t < 6; ++t)
        wfr[t] = *(const short8*)(Wf + ((size_t)((hg * 8 + kqg) * 6 + t) * 64 + lane) * 8);
#pragma unroll
      for (int pt = 0; pt < 4; ++pt){
        aqT[0][pt] = MFMA16(wfr[0], xf[pt], aqT[0][pt]);   // D[ch][px]
        aqT[1][pt] = MFMA16(wfr[1], xf[pt], aqT[1][pt]);
        akT[0][pt] = MFMA16(wfr[2], xf[pt], akT[0][pt]);
        akT[1][pt] = MFMA16(wfr[3], xf[pt], akT[1][pt]);
        avN[pt][0] = MFMA16(xf[pt], wfr[4], avN[pt][0]);   // D[px][ch]
        avN[pt][1] = MFMA16(xf[pt], wfr[5], avN[pt][1]);
      }
    }
    if (half == 0){
      __syncthreads();                       // all half0 x reads done
#pragma unroll
      for (int it = 0; it < 4; ++it){
        int chunk = it * 256 + tid;
        if (chunk < 784) GLL16(xwin + 8192 + chunk * 8, lds + chunk * 8);
      }
      __syncthreads();                       // half1 landed
    }
  }

  // write q,k -> [px][128ch swz], b64-packed (lane rows = 4 consecutive ch)
#pragma unroll
  for (int t = 0; t < 2; ++t)
#pragma unroll
    for (int pt = 0; pt < 4; ++pt){
      int px = pt * 16 + (lane & 15);
      int ck = hl * 4 + t * 2 + ((lane >> 4) >> 1);     // chl>>3, const over j
      int sub = ((lane >> 4) & 1) * 4;                  // chl&7 base
      int pos = px * 128 + (((ck & 8) | ((ck ^ px) & 7)) << 3) + sub;
      *(unsigned long long*)(lds + 8192 + pos)  = pack4(aqT[t][pt]);
      *(unsigned long long*)(lds + 16384 + pos) = pack4(akT[t][pt]);
    }
  __syncthreads();                           // all ph1 x reads done -> x region becomes vT
  // write vT -> [128ch][64px swz], b64-packed (lane rows = 4 consecutive px)
#pragma unroll
  for (int ct = 0; ct < 2; ++ct)
#pragma unroll
    for (int pt = 0; pt < 4; ++pt){
      int chl = hl * 32 + ct * 16 + (lane & 15);
      int pxb = pt * 16 + ((lane >> 4) << 2);
      int addr = chl * 64 + (((pxb >> 3) ^ (chl & 7)) << 3) + (pxb & 7);
      *(unsigned long long*)(lds + addr) = pack4(avN[pt][ct]);
    }

  // ---- phase 2: S^T = K * Q^T (own head's q,k) ----
  short8 kf[4], qf[4];
#pragma unroll
  for (int i = 0; i < 4; ++i){
    int px = i * 16 + (lane & 15);
    int c = hl * 4 + (lane >> 4);            // own head's chunks
    int cs = (c & 8) | ((c ^ px) & 7);
    qf[i] = *(const short8*)(lds + 8192 + px * 128 + cs * 8);
    kf[i] = *(const short8*)(lds + 16384 + px * 128 + cs * 8);
  }
  f32x4 s[4][4] = {};
#pragma unroll
  for (int mi = 0; mi < 4; ++mi)
#pragma unroll
    for (int ni = 0; ni < 4; ++ni)
      s[mi][ni] = MFMA16(kf[mi], qf[ni], s[mi][ni]);
  __syncthreads();                           // all q/k reads done; q+k region becomes sP

  // ---- softmax over k' per q column; P b64-packed to own sP ----
  // pad rows: x rows 49..63 zeroed -> only kp==48 needs masking (lane<16, r==0 of mi=3)
  const float cexp = 0.25504437f;            // log2(e)/sqrt(32)
  unsigned short* sP = lds + 8192 + hl * 4096;
  bool q0 = (lane < 16);
#pragma unroll
  for (int ni = 0; ni < 4; ++ni){
    float m = s[0][ni][0];
#pragma unroll
    for (int mi = 0; mi < 3; ++mi)
#pragma unroll
      for (int r = 0; r < 4; ++r)
        if (mi | r) m = fmaxf(m, s[mi][ni][r]);
    m = fmaxf(m, q0 ? s[3][ni][0] : -3.0e38f);
    m = fmaxf(m, __shfl_xor(m, 16));
    m = fmaxf(m, __shfl_xor(m, 32));
    float sum = 0.f;
    float pv[4][4];
#pragma unroll
    for (int mi = 0; mi < 3; ++mi)
#pragma unroll
      for (int r = 0; r < 4; ++r){
        float e2 = exp2f((s[mi][ni][r] - m) * cexp);
        pv[mi][r] = e2; sum += e2;
      }
    {
      float e2 = q0 ? exp2f((s[3][ni][0] - m) * cexp) : 0.f;
      pv[3][0] = e2; sum += e2;
      pv[3][1] = 0.f; pv[3][2] = 0.f; pv[3][3] = 0.f;
    }
    sum += __shfl_xor(sum, 16);
    sum += __shfl_xor(sum, 32);
    float inv = 1.0f / sum;
    int q = ni * 16 + (lane & 15);
#pragma unroll
    for (int mi = 0; mi < 4; ++mi){
      int kpb2 = mi * 32 + ((lane >> 4) << 3);          // byte offset of 4-kp group
      int bo = (q * 128 + kpb2) ^ ((q & 7) << 4);
      unsigned long long pk =
          (unsigned long long)f2bf(pv[mi][0] * inv)
        | ((unsigned long long)f2bf(pv[mi][1] * inv) << 16)
        | ((unsigned long long)f2bf(pv[mi][2] * inv) << 32)
        | ((unsigned long long)f2bf(pv[mi][3] * inv) << 48);
      *(unsigned long long*)((char*)sP + bo) = pk;
    }
  }

  // ---- phase 3: O^T = V^T * P^T (own sP + own vT rows); D[ch][q] ----
  f32x4 oT[2][4] = {};
#pragma unroll
  for (int kc = 0; kc < 2; ++kc){
    short8 pa[4], vb[2];
#pragma unroll
    for (int mtp = 0; mtp < 4; ++mtp){
      int row = mtp * 16 + (lane & 15);
      int bo = (row * 128 + kc * 64 + (lane >> 4) * 16) ^ ((row & 7) << 4);
      pa[mtp] = *(const short8*)((char*)sP + bo);
    }
#pragma unroll
    for (int ntp = 0; ntp < 2; ++ntp){
      int chl = hl * 32 + ntp * 16 + (lane & 15);
      int k0 = kc * 32 + (lane >> 4) * 8;
      vb[ntp] = *(const short8*)(lds + chl * 64 + (((k0 >> 3) ^ (chl & 7)) << 3));
    }
#pragma unroll
    for (int mtp = 0; mtp < 4; ++mtp)
#pragma unroll
      for (int ntp = 0; ntp < 2; ++ntp)
        oT[ntp][mtp] = MFMA16(vb[ntp], pa[mtp], oT[ntp][mtp]);
  }
  // O -> own sP area [64px(q)][32ch swz], b64-packed (lane rows = 4 consecutive ch)
#pragma unroll
  for (int ntp = 0; ntp < 2; ++ntp)
#pragma unroll
    for (int mtp = 0; mtp < 4; ++mtp){
      int px = mtp * 16 + (lane & 15);
      int chb = ntp * 16 + ((lane >> 4) << 2);
      int c2 = chb >> 3;
      int addr = px * 32 + (((c2 ^ px) & 3) << 3) + (chb & 7);
      *(unsigned long long*)(sP + addr) = pack4(oT[ntp][mtp]);
    }
  __syncthreads();

  // ---- phase 4: cooperative 16B panel stores (this block's 4 heads) ----
  size_t pb0 = (size_t)b * 392 * 4;
#pragma unroll
  for (int it = 0; it < 4; ++it){
    int id = it * 256 + tid;                 // 0..1023 = 64px * 16 chunks
    int px = id >> 4, ck = id & 15;
    if (px < 49){
      int hl2 = ck >> 2, c2 = ck & 3;
      short8 v = *(const short8*)(lds + 8192 + hl2 * 4096 + px * 32 + (((c2 ^ px) & 3) << 3));
      int ch0 = (hh * 4 + hl2) * 32 + c2 * 8;
      int pg = (wh * 7 + px / 7) * 224 + ww * 7 + px % 7;
      int nt = pg >> 7, pr = pg & 127;
      size_t off = (pb0 + (size_t)nt * 4 + (ch0 >> 6)) * 8192 + panel_off(pr, ch0 & 63);
      *(short8*)(attnP + off) = v;
    }
  }
}

// ---------------- GEMM out + residual (bf16 y) + per-block BN partials ----------------
__global__ __launch_bounds__(256) void k_gemm_out(const unsigned short* __restrict__ Wp,
                                                  const unsigned short* __restrict__ Bp,
                                                  const float* __restrict__ x,
                                                  unsigned short* __restrict__ ybf,
                                                  float* __restrict__ partials){
  int bid = blockIdx.x;
  int wg = (bid & 7) * 392 + (bid >> 3);     // 3136 = 8*392
  int mt = wg & 1; int rest = wg >> 1;       // mt fastest
  int nt = rest % 392; int b = rest / 392;

  __shared__ __align__(16) unsigned short lds[32768];  // dbuf

  int tid = threadIdx.x;
  int lane = tid & 63;
  int wave = tid >> 6;
  int wm = wave >> 1, wn = wave & 1;

  const unsigned short* Apan = Wp + (size_t)mt * 4 * 8192;
  const unsigned short* Bpan = Bp + ((size_t)(b * 392 + nt)) * 4 * 8192;

  int aoff[2][4], boff[2][4];
#pragma unroll
  for (int kk = 0; kk < 2; ++kk)
#pragma unroll
    for (int i = 0; i < 4; ++i){
      int rowA = wm * 64 + i * 16 + (lane & 15);
      aoff[kk][i] = rowA * 64 + (((kk * 4 + (lane >> 4)) ^ (rowA & 7)) << 3);
      int rowB = wn * 64 + i * 16 + (lane & 15);
      boff[kk][i] = rowB * 64 + (((kk * 4 + (lane >> 4)) ^ (rowB & 7)) << 3);
    }
  int cb = wave * 2048;
  f32x4 acc[4][4] = {};

#pragma unroll
  for (int j = 0; j < 4; ++j){
    int o2 = cb + j * 512;
    GLL16(Apan + o2 + lane * 8, lds + o2);
    GLL16(Bpan + o2 + lane * 8, lds + 8192 + o2);
  }
  __syncthreads();

  int cur = 0;
  for (int kq = 0; kq < 4; ++kq){
    if (kq < 3){
      const unsigned short* Ak = Apan + (kq + 1) * 8192;
      const unsigned short* Bk = Bpan + (kq + 1) * 8192;
      unsigned short* dst = lds + (cur ^ 1) * 16384;
#pragma unroll
      for (int j = 0; j < 4; ++j){
        int o2 = cb + j * 512;
        GLL16(Ak + o2 + lane * 8, dst + o2);
        GLL16(Bk + o2 + lane * 8, dst + 8192 + o2);
      }
    }
    const unsigned short* Alds = lds + cur * 16384;
    const unsigned short* Blds = Alds + 8192;
#pragma unroll
    for (int kk = 0; kk < 2; ++kk){
      short8 af[4], bfv[4];
#pragma unroll
      for (int i = 0; i < 4; ++i) af[i]  = *(const short8*)(Alds + aoff[kk][i]);
#pragma unroll
      for (int j = 0; j < 4; ++j) bfv[j] = *(const short8*)(Blds + boff[kk][j]);
#pragma unroll
      for (int i = 0; i < 4; ++i)
#pragma unroll
        for (int j = 0; j < 4; ++j)
          acc[i][j] = MFMA16(af[i], bfv[j], acc[i][j]);
    }
    __syncthreads();
    cur ^= 1;
  }
  // epilogue: residual add, bf16 y store, per-channel partial sums
  float ps[4][4] = {}, pq[4][4] = {};
#pragma unroll
  for (int i = 0; i < 4; ++i)
#pragma unroll
    for (int j = 0; j < 4; ++j){
      int o = mt * 128 + wm * 64 + i * 16 + (lane >> 4) * 4;
      int p = nt * 128 + wn * 64 + j * 16 + (lane & 15);
      size_t base = ((size_t)(b * 256 + o)) * HW_ + p;
#pragma unroll
      for (int r2 = 0; r2 < 4; ++r2){
        float v = acc[i][j][r2] + x[base + (size_t)r2 * HW_];
        ybf[base + (size_t)r2 * HW_] = f2bf(v);
        ps[i][r2] += v;
        pq[i][r2] += v * v;
      }
    }
  float* fl = (float*)lds;    // [wn 2][cl 128] sums, +256 sq
#pragma unroll
  for (int i = 0; i < 4; ++i)
#pragma unroll
    for (int r2 = 0; r2 < 4; ++r2){
      float a = ps[i][r2], q2 = pq[i][r2];
      a += __shfl_xor(a, 1);  q2 += __shfl_xor(q2, 1);
      a += __shfl_xor(a, 2);  q2 += __shfl_xor(q2, 2);
      a += __shfl_xor(a, 4);  q2 += __shfl_xor(q2, 4);
      a += __shfl_xor(a, 8);  q2 += __shfl_xor(q2, 8);
      if ((lane & 15) == 0){
        int cl = wm * 64 + i * 16 + (lane >> 4) * 4 + r2;
        fl[wn * 128 + cl] = a;
        fl[256 + wn * 128 + cl] = q2;
      }
    }
  __syncthreads();
  if (tid < 128){
    partials[(size_t)wg * 256 + tid]       = fl[tid] + fl[128 + tid];
    partials[(size_t)wg * 256 + 128 + tid] = fl[256 + tid] + fl[384 + tid];
  }
}

// ---------------- reduce per-block partials -> mean / rsqrt ----------------
__global__ __launch_bounds__(256) void k_stats2(const float* __restrict__ partials, float* __restrict__ stats){
  int c = blockIdx.x;           // 0..255
  int mt = c >> 7, cl = c & 127;
  int t = threadIdx.x;
  float s = 0.f, q = 0.f;
  for (int idx = t; idx < 1568; idx += 256){
    const float* p = partials + (size_t)(2 * idx + mt) * 256;
    s += p[cl]; q += p[128 + cl];
  }
  __shared__ float r1[256], r2[256];
  r1[t] = s; r2[t] = q; __syncthreads();
  for (int off = 128; off > 0; off >>= 1){
    if (t < off){ r1[t] += r1[t + off]; r2[t] += r2[t + off]; }
    __syncthreads();
  }
  if (t == 0){
    float mean = r1[0] * (1.f / 200704.f);
    float var  = r2[0] * (1.f / 200704.f) - mean * mean;
    stats[c] = mean;
    stats[256 + c] = rsqrtf(var + 1e-5f);
  }
}

// ---------------- normalize: bf16 y -> fp32 out ----------------
__global__ __launch_bounds__(256) void k_norm(const unsigned short* __restrict__ ybf,
                                              const float* __restrict__ stats,
                                              const float* __restrict__ gamma, const float* __restrict__ beta,
                                              float* __restrict__ out){
  const long long total = 6422528LL;   // 51380224 / 8
  for (long long idx = (long long)blockIdx.x * 256 + threadIdx.x; idx < total; idx += (long long)gridDim.x * 256){
    int c = (int)((idx / 6272) & 255);  // 6272 = 50176/8
    float sc = stats[256 + c] * gamma[c];
    float sh = beta[c] - stats[c] * sc;
    short8 v = *(const short8*)(ybf + idx * 8);
    float4 o0, o1;
    o0.x = bf2f((unsigned short)v[0]) * sc + sh;
    o0.y = bf2f((unsigned short)v[1]) * sc + sh;
    o0.z = bf2f((unsigned short)v[2]) * sc + sh;
    o0.w = bf2f((unsigned short)v[3]) * sc + sh;
    o1.x = bf2f((unsigned short)v[4]) * sc + sh;
    o1.y = bf2f((unsigned short)v[5]) * sc + sh;
    o1.z = bf2f((unsigned short)v[6]) * sc + sh;
    o1.w = bf2f((unsigned short)v[7]) * sc + sh;
    *(float4*)(out + idx * 8)     = o0;
    *(float4*)(out + idx * 8 + 4) = o1;
  }
}

extern "C" void kernel_launch(void* const* d_in, const int* in_sizes, int n_in,
                              void* d_out, int out_size, void* d_ws, size_t ws_size,
                              hipStream_t stream){
  const float* x     = (const float*)d_in[0];
  const float* Wq    = (const float*)d_in[1];
  const float* Wk    = (const float*)d_in[2];
  const float* Wv    = (const float*)d_in[3];
  const float* Wo    = (const float*)d_in[4];
  const float* gamma = (const float*)d_in[5];
  const float* beta  = (const float*)d_in[6];
  float* out = (float*)d_out;

  char* ws = (char*)d_ws;
  unsigned short* Wf     = (unsigned short*)ws;                               // 393216 B
  unsigned short* Wo_b   = (unsigned short*)(ws + 393216);                    // 131072 B
  float*          stats  = (float*)(ws + 524288);                             // 2048 B
  unsigned short* xw     = (unsigned short*)(ws + 1048576);                   // 134217728 B
  unsigned short* attnP  = (unsigned short*)(ws + 1048576 + 134217728);       // 102760448 B
  float*          partials = (float*)(ws + 1048576 + 134217728 + 102760448);  // 3211264 B
  unsigned short* ybf    = xw;   // alias: xw dead after k_fused (stream-ordered)

  k_convw<<<128, 256, 0, stream>>>(Wq, Wk, Wv, Wo, Wf, Wo_b);
  k_xw<<<2048, 256, 0, stream>>>(x, xw);
  k_fused<<<8192, 256, 0, stream>>>(xw, Wf, attnP);
  k_gemm_out<<<3136, 256, 0, stream>>>(Wo_b, attnP, x, ybf, partials);
  k_stats2<<<256, 256, 0, stream>>>(partials, stats);
  k_norm<<<4096, 256, 0, stream>>>(ybf, stats, gamma, beta, out);
}

// Round 12
// 448.511 us; speedup vs baseline: 1.1634x; 1.0496x over previous
//
#include <hip/hip_runtime.h>
#include <stdint.h>

typedef __attribute__((ext_vector_type(8))) short short8;
typedef __attribute__((ext_vector_type(4))) float f32x4;

#define MFMA16(a,b,c) __builtin_amdgcn_mfma_f32_16x16x32_bf16((a),(b),(c),0,0,0)

// async global->LDS DMA, 16B per lane; LDS dest = wave-uniform base + lane*16B
#define GLL16(g, l) __builtin_amdgcn_global_load_lds( \
    (const __attribute__((address_space(1))) void*)(g), \
    (__attribute__((address_space(3))) void*)(l), 16, 0, 0)

__device__ __forceinline__ unsigned short f2bf(float f){
  unsigned u = __builtin_bit_cast(unsigned, f);
  u += 0x7fffu + ((u >> 16) & 1u);
  return (unsigned short)(u >> 16);
}
__device__ __forceinline__ float bf2f(unsigned short s){
  unsigned u = ((unsigned)s) << 16;
  return __builtin_bit_cast(float, u);
}
// pack 4 f32 -> 4 bf16 in a u64 (RNE, proven f2bf path)
__device__ __forceinline__ unsigned long long pack4(f32x4 v){
  return (unsigned long long)f2bf(v[0])
       | ((unsigned long long)f2bf(v[1]) << 16)
       | ((unsigned long long)f2bf(v[2]) << 32)
       | ((unsigned long long)f2bf(v[3]) << 48);
}

static constexpr int HW_ = 50176;   // 224*224

// offset of element (row r 0..127, k c64 0..63) inside one 8192-elem panel,
// XOR-swizzled so ds_read_b128 of a 16-lane column slice is conflict-free
__device__ __forceinline__ int panel_off(int r, int c64){
  return r * 64 + ((((c64 >> 3) ^ (r & 7))) << 3) + (c64 & 7);
}

// ---------------- weights fp32 -> bf16 ----------------
__global__ __launch_bounds__(256) void k_convw(const float* __restrict__ Wq, const float* __restrict__ Wk,
                        const float* __restrict__ Wv, const float* __restrict__ Wo,
                        unsigned short* __restrict__ Wf, unsigned short* __restrict__ Wob){
  int gid = blockIdx.x * 256 + threadIdx.x;   // grid 128 -> 32768
  if (gid < 24576){
    int lane = gid & 63;
    int r1 = gid >> 6;          // 0..383
    int t = r1 % 6;
    int r2 = r1 / 6;            // 0..63
    int kq = r2 & 7, hh = r2 >> 3;
    const float* W = (t < 2) ? Wq : (t < 4) ? Wk : Wv;
    int ch = hh * 32 + (t & 1) * 16 + (lane & 15);
    int k0 = kq * 32 + (lane >> 4) * 8;
    const float* src = W + ch * 256 + k0;
    float4 a = *(const float4*)src, b2 = *(const float4*)(src + 4);
    short8 v;
    v[0]=f2bf(a.x); v[1]=f2bf(a.y); v[2]=f2bf(a.z); v[3]=f2bf(a.w);
    v[4]=f2bf(b2.x); v[5]=f2bf(b2.y); v[6]=f2bf(b2.z); v[7]=f2bf(b2.w);
    *(short8*)(Wf + (size_t)gid * 8) = v;
  } else {
    int og = gid - 24576;       // 0..8191
    int o = og >> 5, ck = og & 31;
    const float* src = Wo + o * 256 + ck * 8;
    float4 a = *(const float4*)src, b2 = *(const float4*)(src + 4);
    short8 v;
    v[0]=f2bf(a.x); v[1]=f2bf(a.y); v[2]=f2bf(a.z); v[3]=f2bf(a.w);
    v[4]=f2bf(b2.x); v[5]=f2bf(b2.y); v[6]=f2bf(b2.z); v[7]=f2bf(b2.w);
    int kq = ck >> 3;
    int off = panel_off(o & 127, (ck & 7) * 8);
    *(short8*)(Wob + ((o >> 7) * 4 + kq) * 8192 + off) = v;
  }
}

// ---------------- x (B,C,H,W) f32 -> xw[win][half 2][px 49/64][128c swz] bf16 ----------------
__global__ __launch_bounds__(256) void k_xw(const float* __restrict__ x, unsigned short* __restrict__ xw){
  int bid = blockIdx.x;
  int cq = bid & 15, wh = (bid >> 4) & 31, b = bid >> 9;
  __shared__ __align__(16) unsigned short tile[25088];  // 49 KB
  int tid = threadIdx.x;
  for (int it = 0; it < 25; ++it){
    int idx = it * 256 + tid;
    if (idx < 6272){
      int c = idx & 15;
      int t2 = idx >> 4;                  // 0..391
      int r = t2 / 56;
      int w4 = t2 % 56;
      float4 v = *(const float4*)(x + ((size_t)(b * 256 + cq * 16 + c)) * HW_ + (wh * 7 + r) * 224 + w4 * 4);
      float vv[4] = {v.x, v.y, v.z, v.w};
      int w0 = w4 * 4;
      int ww = w0 / 7;
      int cl = w0 % 7;
#pragma unroll
      for (int i = 0; i < 4; ++i){
        int px = r * 7 + cl;
        tile[ww * 784 + px * 16 + (((c >> 3) ^ (px & 1)) << 3) + (c & 7)] = f2bf(vv[i]);
        if (++cl == 7){ cl = 0; ++ww; }
      }
    }
  }
  __syncthreads();
  size_t wb = ((size_t)(b * 1024 + wh * 32)) * 16384;
  for (int it = 0; it < 13; ++it){
    int id = it * 256 + tid;
    if (id < 3136){                       // 32 ww x 49 px x 2 chunk-slots
      int ww = id / 98;
      int rem = id - ww * 98;
      int px = rem >> 1, hb = rem & 1;
      short8 v = *(const short8*)(tile + ww * 784 + px * 16 + ((hb ^ (px & 1)) << 3));
      int cc = cq * 2 + hb;               // global 8-ch chunk 0..31
      int half = cc >> 4, c4 = cc & 15;
      int pos = (c4 & 8) | ((c4 ^ px) & 7);
      *(short8*)(xw + wb + (size_t)ww * 16384 + half * 8192 + px * 128 + pos * 8) = v;
    }
  }
}

// ---------------- fused: qkv GEMM + window attention ----------------
// block = (window, 4-head half), 4 waves = 4 heads, 48 KB LDS -> 3 blocks/CU
// x0 at [0,8192), x1 at [8192,16384) (overlapped DMA, counted vmcnt);
// q overwrites x1, vT overwrites x0 after a single post-phase-1 barrier.
__global__ __launch_bounds__(256, 3) void k_fused(const unsigned short* __restrict__ xw,
                                                  const unsigned short* __restrict__ Wf,
                                                  unsigned short* __restrict__ attnP){
  int bid = blockIdx.x;
  int wg = (bid & 7) * 1024 + (bid >> 3);   // 8192 = 8*1024; window pair on same XCD
  int hh = wg & 1; int win = wg >> 1;
  int b = win >> 10;
  int wh = (win >> 5) & 31, ww = win & 31;
  int tid = threadIdx.x;
  int lane = tid & 63;
  int hl = tid >> 6;                         // local head 0..3
  int hg = hh * 4 + hl;                      // global head

  __shared__ __align__(16) unsigned short lds[24576];   // 48 KB

  const unsigned short* xwin = xw + (size_t)win * 16384;

  // ---- phase 0: zero pad rows 49..63 of BOTH x buffers + overlapped DMA ----
  if (tid < 240){
    int rr = 49 + (tid >> 4), ck = tid & 15;
    short8 z = {};
    *(short8*)(lds + rr * 128 + ck * 8) = z;
    *(short8*)(lds + 8192 + rr * 128 + ck * 8) = z;
  }
#pragma unroll
  for (int it = 0; it < 4; ++it){
    int chunk = it * 256 + tid;              // x half0 -> [0,8192)
    if (chunk < 784) GLL16(xwin + chunk * 8, lds + chunk * 8);
  }
#pragma unroll
  for (int it = 0; it < 4; ++it){
    int chunk = it * 256 + tid;              // x half1 -> [8192,16384), stays in flight
    if (chunk < 784) GLL16(xwin + 8192 + chunk * 8, lds + 8192 + chunk * 8);
  }
  if (hl == 0) asm volatile("s_waitcnt vmcnt(4) lgkmcnt(0)" ::: "memory");  // wave0: 4 x1 ops remain
  else         asm volatile("s_waitcnt vmcnt(3) lgkmcnt(0)" ::: "memory");  // waves1-3: 3 remain
  __builtin_amdgcn_s_barrier();              // x0 (and zero-fill) visible to all waves

  // ---- phase 1: qkv GEMM; q,k transposed (D[ch][px]); v natural (D[px][ch]) ----
  f32x4 aqT[2][4] = {}, akT[2][4] = {}, avN[4][2] = {};
  for (int half = 0; half < 2; ++half){
    const unsigned short* xb = lds + half * 8192;
    for (int kq = 0; kq < 4; ++kq){
      short8 xf[4];
#pragma unroll
      for (int pt = 0; pt < 4; ++pt){
        int px = pt * 16 + (lane & 15);
        int c = kq * 4 + (lane >> 4);        // chunk 0..15
        int cs = (c & 8) | ((c ^ px) & 7);
        xf[pt] = *(const short8*)(xb + px * 128 + cs * 8);
      }
      short8 wfr[6];
      int kqg = half * 4 + kq;
#pragma unroll
      for (int t = 0; t < 6; ++t)
        wfr[t] = *(const short8*)(Wf + ((size_t)((hg * 8 + kqg) * 6 + t) * 64 + lane) * 8);
#pragma unroll
      for (int pt = 0; pt < 4; ++pt){
        aqT[0][pt] = MFMA16(wfr[0], xf[pt], aqT[0][pt]);   // D[ch][px]
        aqT[1][pt] = MFMA16(wfr[1], xf[pt], aqT[1][pt]);
        akT[0][pt] = MFMA16(wfr[2], xf[pt], akT[0][pt]);
        akT[1][pt] = MFMA16(wfr[3], xf[pt], akT[1][pt]);
        avN[pt][0] = MFMA16(xf[pt], wfr[4], avN[pt][0]);   // D[px][ch]
        avN[pt][1] = MFMA16(xf[pt], wfr[5], avN[pt][1]);
      }
    }
    if (half == 0){
      asm volatile("s_waitcnt vmcnt(0)" ::: "memory");  // own x1 DMAs landed
      __builtin_amdgcn_s_barrier();                     // all waves' x1 landed
    }
  }
  __syncthreads();                           // all x reads done -> x0/x1 become vT/q

  // write q,k -> [px][128ch swz], b64-packed (lane rows = 4 consecutive ch)
#pragma unroll
  for (int t = 0; t < 2; ++t)
#pragma unroll
    for (int pt = 0; pt < 4; ++pt){
      int px = pt * 16 + (lane & 15);
      int ck = hl * 4 + t * 2 + ((lane >> 4) >> 1);     // chl>>3, const over j
      int sub = ((lane >> 4) & 1) * 4;                  // chl&7 base
      int pos = px * 128 + (((ck & 8) | ((ck ^ px) & 7)) << 3) + sub;
      *(unsigned long long*)(lds + 8192 + pos)  = pack4(aqT[t][pt]);   // over x1
      *(unsigned long long*)(lds + 16384 + pos) = pack4(akT[t][pt]);
    }
  // write vT -> x0 region [128ch][64px swz], b64-packed (lane rows = 4 consecutive px)
#pragma unroll
  for (int ct = 0; ct < 2; ++ct)
#pragma unroll
    for (int pt = 0; pt < 4; ++pt){
      int chl = hl * 32 + ct * 16 + (lane & 15);
      int pxb = pt * 16 + ((lane >> 4) << 2);
      int addr = chl * 64 + (((pxb >> 3) ^ (chl & 7)) << 3) + (pxb & 7);
      *(unsigned long long*)(lds + addr) = pack4(avN[pt][ct]);
    }

  // ---- phase 2: S^T = K * Q^T (own head's q,k -- written by THIS wave, in-order LDS) ----
  short8 kf[4], qf[4];
#pragma unroll
  for (int i = 0; i < 4; ++i){
    int px = i * 16 + (lane & 15);
    int c = hl * 4 + (lane >> 4);            // own head's chunks
    int cs = (c & 8) | ((c ^ px) & 7);
    qf[i] = *(const short8*)(lds + 8192 + px * 128 + cs * 8);
    kf[i] = *(const short8*)(lds + 16384 + px * 128 + cs * 8);
  }
  f32x4 s[4][4] = {};
#pragma unroll
  for (int mi = 0; mi < 4; ++mi)
#pragma unroll
    for (int ni = 0; ni < 4; ++ni)
      s[mi][ni] = MFMA16(kf[mi], qf[ni], s[mi][ni]);
  __syncthreads();                           // all q/k reads + vT writes visible; q+k -> sP

  // ---- softmax over k' per q column; P b64-packed to own sP ----
  const float cexp = 0.25504437f;            // log2(e)/sqrt(32)
  unsigned short* sP = lds + 8192 + hl * 4096;
  bool q0 = (lane < 16);
#pragma unroll
  for (int ni = 0; ni < 4; ++ni){
    float m = s[0][ni][0];
#pragma unroll
    for (int mi = 0; mi < 3; ++mi)
#pragma unroll
      for (int r = 0; r < 4; ++r)
        if (mi | r) m = fmaxf(m, s[mi][ni][r]);
    m = fmaxf(m, q0 ? s[3][ni][0] : -3.0e38f);
    m = fmaxf(m, __shfl_xor(m, 16));
    m = fmaxf(m, __shfl_xor(m, 32));
    float sum = 0.f;
    float pv[4][4];
#pragma unroll
    for (int mi = 0; mi < 3; ++mi)
#pragma unroll
      for (int r = 0; r < 4; ++r){
        float e2 = exp2f((s[mi][ni][r] - m) * cexp);
        pv[mi][r] = e2; sum += e2;
      }
    {
      float e2 = q0 ? exp2f((s[3][ni][0] - m) * cexp) : 0.f;
      pv[3][0] = e2; sum += e2;
      pv[3][1] = 0.f; pv[3][2] = 0.f; pv[3][3] = 0.f;
    }
    sum += __shfl_xor(sum, 16);
    sum += __shfl_xor(sum, 32);
    float inv = 1.0f / sum;
    int q = ni * 16 + (lane & 15);
#pragma unroll
    for (int mi = 0; mi < 4; ++mi){
      int kpb2 = mi * 32 + ((lane >> 4) << 3);          // byte offset of 4-kp group
      int bo = (q * 128 + kpb2) ^ ((q & 7) << 4);
      unsigned long long pk =
          (unsigned long long)f2bf(pv[mi][0] * inv)
        | ((unsigned long long)f2bf(pv[mi][1] * inv) << 16)
        | ((unsigned long long)f2bf(pv[mi][2] * inv) << 32)
        | ((unsigned long long)f2bf(pv[mi][3] * inv) << 48);
      *(unsigned long long*)((char*)sP + bo) = pk;
    }
  }

  // ---- phase 3: O^T = V^T * P^T (own sP + own vT rows); D[ch][q] ----
  f32x4 oT[2][4] = {};
#pragma unroll
  for (int kc = 0; kc < 2; ++kc){
    short8 pa[4], vb[2];
#pragma unroll
    for (int mtp = 0; mtp < 4; ++mtp){
      int row = mtp * 16 + (lane & 15);
      int bo = (row * 128 + kc * 64 + (lane >> 4) * 16) ^ ((row & 7) << 4);
      pa[mtp] = *(const short8*)((char*)sP + bo);
    }
#pragma unroll
    for (int ntp = 0; ntp < 2; ++ntp){
      int chl = hl * 32 + ntp * 16 + (lane & 15);
      int k0 = kc * 32 + (lane >> 4) * 8;
      vb[ntp] = *(const short8*)(lds + chl * 64 + (((k0 >> 3) ^ (chl & 7)) << 3));
    }
#pragma unroll
    for (int mtp = 0; mtp < 4; ++mtp)
#pragma unroll
      for (int ntp = 0; ntp < 2; ++ntp)
        oT[ntp][mtp] = MFMA16(vb[ntp], pa[mtp], oT[ntp][mtp]);
  }
  // O -> own sP area [64px(q)][32ch swz], b64-packed (lane rows = 4 consecutive ch)
#pragma unroll
  for (int ntp = 0; ntp < 2; ++ntp)
#pragma unroll
    for (int mtp = 0; mtp < 4; ++mtp){
      int px = mtp * 16 + (lane & 15);
      int chb = ntp * 16 + ((lane >> 4) << 2);
      int c2 = chb >> 3;
      int addr = px * 32 + (((c2 ^ px) & 3) << 3) + (chb & 7);
      *(unsigned long long*)(sP + addr) = pack4(oT[ntp][mtp]);
    }
  __syncthreads();

  // ---- phase 4: cooperative 16B panel stores (this block's 4 heads) ----
  size_t pb0 = (size_t)b * 392 * 4;
#pragma unroll
  for (int it = 0; it < 4; ++it){
    int id = it * 256 + tid;                 // 0..1023 = 64px * 16 chunks
    int px = id >> 4, ck = id & 15;
    if (px < 49){
      int hl2 = ck >> 2, c2 = ck & 3;
      short8 v = *(const short8*)(lds + 8192 + hl2 * 4096 + px * 32 + (((c2 ^ px) & 3) << 3));
      int ch0 = (hh * 4 + hl2) * 32 + c2 * 8;
      int pg = (wh * 7 + px / 7) * 224 + ww * 7 + px % 7;
      int nt = pg >> 7, pr = pg & 127;
      size_t off = (pb0 + (size_t)nt * 4 + (ch0 >> 6)) * 8192 + panel_off(pr, ch0 & 63);
      *(short8*)(attnP + off) = v;
    }
  }
}

// ---------------- GEMM out + residual (bf16 y) + per-block BN partials ----------------
// counted-vmcnt 2-deep pipeline: next tile's 8 loads stay in flight across barriers
__global__ __launch_bounds__(256) void k_gemm_out(const unsigned short* __restrict__ Wp,
                                                  const unsigned short* __restrict__ Bp,
                                                  const float* __restrict__ x,
                                                  unsigned short* __restrict__ ybf,
                                                  float* __restrict__ partials){
  int bid = blockIdx.x;
  int wg = (bid & 7) * 392 + (bid >> 3);     // 3136 = 8*392
  int mt = wg & 1; int rest = wg >> 1;       // mt fastest
  int nt = rest % 392; int b = rest / 392;

  __shared__ __align__(16) unsigned short lds[32768];  // dbuf (2 x 32KB)

  int tid = threadIdx.x;
  int lane = tid & 63;
  int wave = tid >> 6;
  int wm = wave >> 1, wn = wave & 1;

  const unsigned short* Apan = Wp + (size_t)mt * 4 * 8192;
  const unsigned short* Bpan = Bp + ((size_t)(b * 392 + nt)) * 4 * 8192;

  int aoff[2][4], boff[2][4];
#pragma unroll
  for (int kk = 0; kk < 2; ++kk)
#pragma unroll
    for (int i = 0; i < 4; ++i){
      int rowA = wm * 64 + i * 16 + (lane & 15);
      aoff[kk][i] = rowA * 64 + (((kk * 4 + (lane >> 4)) ^ (rowA & 7)) << 3);
      int rowB = wn * 64 + i * 16 + (lane & 15);
      boff[kk][i] = rowB * 64 + (((kk * 4 + (lane >> 4)) ^ (rowB & 7)) << 3);
    }
  int cb = wave * 2048;
  f32x4 acc[4][4] = {};

  // prologue: T0 -> buf0, T1 -> buf1 (16 loads in flight per wave)
#pragma unroll
  for (int j = 0; j < 4; ++j){
    int o2 = cb + j * 512;
    GLL16(Apan + o2 + lane * 8, lds + o2);
    GLL16(Bpan + o2 + lane * 8, lds + 8192 + o2);
  }
#pragma unroll
  for (int j = 0; j < 4; ++j){
    int o2 = cb + j * 512;
    GLL16(Apan + 8192 + o2 + lane * 8, lds + 16384 + o2);
    GLL16(Bpan + 8192 + o2 + lane * 8, lds + 24576 + o2);
  }

  int cur = 0;
  for (int kq = 0; kq < 4; ++kq){
    if (kq < 3) asm volatile("s_waitcnt vmcnt(8)" ::: "memory");  // tile kq landed; next stays in flight
    else        asm volatile("s_waitcnt vmcnt(0)" ::: "memory");
    __builtin_amdgcn_s_barrier();
    const unsigned short* Alds = lds + cur * 16384;
    const unsigned short* Blds = Alds + 8192;
#pragma unroll
    for (int kk = 0; kk < 2; ++kk){
      short8 af[4], bfv[4];
#pragma unroll
      for (int i = 0; i < 4; ++i) af[i]  = *(const short8*)(Alds + aoff[kk][i]);
#pragma unroll
      for (int j = 0; j < 4; ++j) bfv[j] = *(const short8*)(Blds + boff[kk][j]);
#pragma unroll
      for (int i = 0; i < 4; ++i)
#pragma unroll
        for (int j = 0; j < 4; ++j)
          acc[i][j] = MFMA16(af[i], bfv[j], acc[i][j]);
    }
    asm volatile("s_waitcnt lgkmcnt(0)" ::: "memory");   // this wave's LDS reads consumed
    __builtin_amdgcn_s_barrier();                        // all waves done reading buf[cur]
    if (kq < 2){
      const unsigned short* Ak = Apan + (kq + 2) * 8192;
      const unsigned short* Bk = Bpan + (kq + 2) * 8192;
      unsigned short* dst = lds + cur * 16384;
#pragma unroll
      for (int j = 0; j < 4; ++j){
        int o2 = cb + j * 512;
        GLL16(Ak + o2 + lane * 8, dst + o2);
        GLL16(Bk + o2 + lane * 8, dst + 8192 + o2);
      }
    }
    cur ^= 1;
  }
  // epilogue: residual add, bf16 y store, per-channel partial sums
  float ps[4][4] = {}, pq[4][4] = {};
#pragma unroll
  for (int i = 0; i < 4; ++i)
#pragma unroll
    for (int j = 0; j < 4; ++j){
      int o = mt * 128 + wm * 64 + i * 16 + (lane >> 4) * 4;
      int p = nt * 128 + wn * 64 + j * 16 + (lane & 15);
      size_t base = ((size_t)(b * 256 + o)) * HW_ + p;
#pragma unroll
      for (int r2 = 0; r2 < 4; ++r2){
        float v = acc[i][j][r2] + x[base + (size_t)r2 * HW_];
        ybf[base + (size_t)r2 * HW_] = f2bf(v);
        ps[i][r2] += v;
        pq[i][r2] += v * v;
      }
    }
  float* fl = (float*)lds;    // [wn 2][cl 128] sums, +256 sq
#pragma unroll
  for (int i = 0; i < 4; ++i)
#pragma unroll
    for (int r2 = 0; r2 < 4; ++r2){
      float a = ps[i][r2], q2 = pq[i][r2];
      a += __shfl_xor(a, 1);  q2 += __shfl_xor(q2, 1);
      a += __shfl_xor(a, 2);  q2 += __shfl_xor(q2, 2);
      a += __shfl_xor(a, 4);  q2 += __shfl_xor(q2, 4);
      a += __shfl_xor(a, 8);  q2 += __shfl_xor(q2, 8);
      if ((lane & 15) == 0){
        int cl = wm * 64 + i * 16 + (lane >> 4) * 4 + r2;
        fl[wn * 128 + cl] = a;
        fl[256 + wn * 128 + cl] = q2;
      }
    }
  __syncthreads();
  if (tid < 128){
    partials[(size_t)wg * 256 + tid]       = fl[tid] + fl[128 + tid];
    partials[(size_t)wg * 256 + 128 + tid] = fl[256 + tid] + fl[384 + tid];
  }
}

// ---------------- reduce per-block partials -> mean / rsqrt ----------------
__global__ __launch_bounds__(256) void k_stats2(const float* __restrict__ partials, float* __restrict__ stats){
  int c = blockIdx.x;           // 0..255
  int mt = c >> 7, cl = c & 127;
  int t = threadIdx.x;
  float s = 0.f, q = 0.f;
  for (int idx = t; idx < 1568; idx += 256){
    const float* p = partials + (size_t)(2 * idx + mt) * 256;
    s += p[cl]; q += p[128 + cl];
  }
  __shared__ float r1[256], r2[256];
  r1[t] = s; r2[t] = q; __syncthreads();
  for (int off = 128; off > 0; off >>= 1){
    if (t < off){ r1[t] += r1[t + off]; r2[t] += r2[t + off]; }
    __syncthreads();
  }
  if (t == 0){
    float mean = r1[0] * (1.f / 200704.f);
    float var  = r2[0] * (1.f / 200704.f) - mean * mean;
    stats[c] = mean;
    stats[256 + c] = rsqrtf(var + 1e-5f);
  }
}

// ---------------- normalize: bf16 y -> fp32 out ----------------
__global__ __launch_bounds__(256) void k_norm(const unsigned short* __restrict__ ybf,
                                              const float* __restrict__ stats,
                                              const float* __restrict__ gamma, const float* __restrict__ beta,
                                              float* __restrict__ out){
  const long long total = 6422528LL;   // 51380224 / 8
  for (long long idx = (long long)blockIdx.x * 256 + threadIdx.x; idx < total; idx += (long long)gridDim.x * 256){
    int c = (int)((idx / 6272) & 255);  // 6272 = 50176/8
    float sc = stats[256 + c] * gamma[c];
    float sh = beta[c] - stats[c] * sc;
    short8 v = *(const short8*)(ybf + idx * 8);
    float4 o0, o1;
    o0.x = bf2f((unsigned short)v[0]) * sc + sh;
    o0.y = bf2f((unsigned short)v[1]) * sc + sh;
    o0.z = bf2f((unsigned short)v[2]) * sc + sh;
    o0.w = bf2f((unsigned short)v[3]) * sc + sh;
    o1.x = bf2f((unsigned short)v[4]) * sc + sh;
    o1.y = bf2f((unsigned short)v[5]) * sc + sh;
    o1.z = bf2f((unsigned short)v[6]) * sc + sh;
    o1.w = bf2f((unsigned short)v[7]) * sc + sh;
    *(float4*)(out + idx * 8)     = o0;
    *(float4*)(out + idx * 8 + 4) = o1;
  }
}

extern "C" void kernel_launch(void* const* d_in, const int* in_sizes, int n_in,
                              void* d_out, int out_size, void* d_ws, size_t ws_size,
                              hipStream_t stream){
  const float* x     = (const float*)d_in[0];
  const float* Wq    = (const float*)d_in[1];
  const float* Wk    = (const float*)d_in[2];
  const float* Wv    = (const float*)d_in[3];
  const float* Wo    = (const float*)d_in[4];
  const float* gamma = (const float*)d_in[5];
  const float* beta  = (const float*)d_in[6];
  float* out = (float*)d_out;

  char* ws = (char*)d_ws;
  unsigned short* Wf     = (unsigned short*)ws;                               // 393216 B
  unsigned short* Wo_b   = (unsigned short*)(ws + 393216);                    // 131072 B
  float*          stats  = (float*)(ws + 524288);                             // 2048 B
  unsigned short* xw     = (unsigned short*)(ws + 1048576);                   // 134217728 B
  unsigned short* attnP  = (unsigned short*)(ws + 1048576 + 134217728);       // 102760448 B
  float*          partials = (float*)(ws + 1048576 + 134217728 + 102760448);  // 3211264 B
  unsigned short* ybf    = xw;   // alias: xw dead after k_fused (stream-ordered)

  k_convw<<<128, 256, 0, stream>>>(Wq, Wk, Wv, Wo, Wf, Wo_b);
  k_xw<<<2048, 256, 0, stream>>>(x, xw);
  k_fused<<<8192, 256, 0, stream>>>(xw, Wf, attnP);
  k_gemm_out<<<3136, 256, 0, stream>>>(Wo_b, attnP, x, ybf, partials);
  k_stats2<<<256, 256, 0, stream>>>(partials, stats);
  k_norm<<<4096, 256, 0, stream>>>(ybf, stats, gamma, beta, out);
}